// Round 9
// baseline (237.577 us; speedup 1.0000x reference)
//
#include <hip/hip_runtime.h>
#include <hip/hip_bf16.h>
#include <hip/hip_fp16.h>

// Pipeline:
//  x (4,64,130,130) --conv3x3 valid + bias + maxpool2x2 (MFMA)--> p1 (4,64,64,64)
//  p1 --[FUSED k_conv13: 1x1 (64->32) MFMA in LDS + 3x3 pad=1 MFMA]--> t3
//  [FUSED] offset conv (32->1152) computed INSIDE k_deform via f16 MFMA
//  deform_conv(x, upsample2x(offsets), wd) -> out (4,64,128,128)
//
//  Round-9 change (k_deform phase-1b only):
//   - Gather ILP batching: 3 groups of 3 tasks. Sub-loop 1 computes all 3
//     address sets and ISSUES 18 fast-path float2 loads into Ld[3][6]
//     registers; sub-loop 2 selects/lerps/writes. Consuming task u waits
//     at vmcnt(12/6/0) while later tasks' loads stay in flight -> exposed
//     L2/L3 latency per group ~3x lower. (Compiler at VGPR=76 was NOT
//     pipelining across tasks; cap is 168 at 3 waves/SIMD, Ld adds ~36.)
//     Fully-unrolled u-loops -> static indexing, no scratch (rule #20);
//     WRITE_SIZE==16.4MB is the spill sentinel.
//   - Everything else = round-8 (v5 body + neutral XCD swizzle + setprio;
//     conv kernels round-7 proven).

#define HX 130
#define WX 130

typedef short bf16x8 __attribute__((ext_vector_type(8)));
typedef _Float16 f16x8 __attribute__((ext_vector_type(8)));
typedef float f32x4 __attribute__((ext_vector_type(4)));

static __device__ __forceinline__ unsigned short f2bf(float f) {
    unsigned u = __float_as_uint(f);
    unsigned r = u + 0x7fff + ((u >> 16) & 1);   // round-to-nearest-even
    return (unsigned short)(r >> 16);
}

// A-tile address (in shorts): row pitch 320, 16B-block swizzle (k_deform v5)
static __device__ __forceinline__ int aoff320(int row, int col) {
    return row * 320 + ((((col >> 3) ^ (row & 7))) << 3) + (col & 7);
}

// A-tile address (in shorts): row pitch 192 (160-col tiles), 16B-block swizzle
static __device__ __forceinline__ int aoff192(int row, int col) {
    return row * 192 + ((((col >> 3) ^ (row & 7))) << 3) + (col & 7);
}

// A-tile address (in shorts): row pitch 80 (64-col 1x1 tile), same family
static __device__ __forceinline__ int aoff80(int row, int col) {
    return row * 80 + ((((col >> 3) ^ (row & 7))) << 3) + (col & 7);
}

// ---------------- K0: weight prep
//  idx <  36864 : wd -> bf16 wdtb[h(2)][oc(64)][col(288)]  (+16 zero tail)
//  idx <  73728 : w3 -> fp16 w3h[1152][32]
//  idx < 114688 : w0 -> bf16 w0b[cig(4)][oc(64)][160]; col=ci_l*9+kk, pad 0
//  idx < 124928 : w2 -> bf16 w2b[cig(2)][oc(32)][160]; col=ci_l*9+kk, pad 0
//  idx < 126976 : w1 -> bf16 w1b[oc(32)][64] (contiguous copy-convert)
__global__ __launch_bounds__(256) void k_wdt(const float* __restrict__ wd,
                                             const float* __restrict__ w3,
                                             const float* __restrict__ w0,
                                             const float* __restrict__ w2,
                                             const float* __restrict__ w1,
                                             unsigned short* __restrict__ wdtb,
                                             __half* __restrict__ w3h,
                                             unsigned short* __restrict__ w0b,
                                             unsigned short* __restrict__ w2b,
                                             unsigned short* __restrict__ w1b) {
    int idx = blockIdx.x * 256 + threadIdx.x;   // grid 496*256 = 126976
    if (idx < 36864) {
        int o = idx / 576;
        int rem = idx - o * 576;
        int c = rem / 9;
        int kk = rem - c * 9;
        int h = c >> 5;
        int c5 = c & 31;
        int col = (c5 >> 4) * 144 + ((c5 >> 3) & 1) * 72 + (c5 & 7) * 9 + kk;
        wdtb[(size_t)(h * 64 + o) * 288 + col] = f2bf(wd[idx]);
        if (idx < 16) wdtb[36864 + idx] = 0;    // tail pad: guard 0*NaN
    } else if (idx < 73728) {
        int i2 = idx - 36864;
        w3h[i2] = __float2half_rn(w3[i2]);
    } else if (idx < 114688) {
        int i3 = idx - 73728;                   // 0..40959
        int row = i3 / 160;                     // cig*64 + oc
        int col = i3 - row * 160;
        int cig = row >> 6, oc = row & 63;
        unsigned short v = 0;
        if (col < 144) {
            int ci = (col * 57) >> 9;           // /9, valid col<144
            int kk = col - ci * 9;
            v = f2bf(w0[(size_t)(oc * 64 + cig * 16 + ci) * 9 + kk]);
        }
        w0b[i3] = v;
    } else if (idx < 124928) {
        int i4 = idx - 114688;                  // 0..10239
        int row = i4 / 160;                     // cig*32 + oc
        int col = i4 - row * 160;
        int cig = row >> 5, oc = row & 31;
        unsigned short v = 0;
        if (col < 144) {
            int ci = (col * 57) >> 9;
            int kk = col - ci * 9;
            v = f2bf(w2[(size_t)(oc * 32 + cig * 16 + ci) * 9 + kk]);
        }
        w2b[i4] = v;
    } else {
        int i5 = idx - 124928;                  // 0..2047
        w1b[i5] = f2bf(w1[i5]);
    }
}

// ---------------- K1: conv3x3 valid (64->64) via MFMA + bias + maxpool -> p1
// grid 1024 = b(4) * ty(16) * tx(16); block 256 = 4 waves. (round-5 proven)
__global__ __launch_bounds__(256, 4) void k_conv0_mfma(const float* __restrict__ x,
                                                       const unsigned short* __restrict__ w0b,
                                                       const float* __restrict__ b0,
                                                       float* __restrict__ p1) {
    int blk = blockIdx.x;
    int tx = blk & 15;
    int ty = (blk >> 4) & 15;
    int b = blk >> 8;
    int tid = threadIdx.x;
    int w = tid >> 6;
    int lane = tid & 63;
    int lm = lane & 15;
    int lq = lane >> 4;
    int oy0 = ty * 8, ox0 = tx * 8;

    __shared__ __align__(16) unsigned short alds[64 * 192];   // 24576 B
    __shared__ __align__(16) float xlds[1600];                //  6400 B

    f32x4 acc[4];
    #pragma unroll
    for (int n = 0; n < 4; ++n) acc[n] = (f32x4){0.f, 0.f, 0.f, 0.f};

    if (tid < 128) {
        *(bf16x8*)&alds[aoff192(tid >> 1, 144 + (tid & 1) * 8)] =
            (bf16x8){0, 0, 0, 0, 0, 0, 0, 0};
    }

    const float* xb = x + (size_t)(b * 64) * (HX * WX) + oy0 * WX + ox0;
    int apx = tid >> 2;           // 0..63 conv px (py*8+pxx)
    int acq = tid & 3;            // col slice
    int py = apx >> 3, pxx = apx & 7;

    for (int cig = 0; cig < 4; ++cig) {
        #pragma unroll
        for (int j = 0; j < 7; ++j) {
            int i = tid + j * 256;
            if (i < 1600) {
                int ci = i / 100;
                int rem = i - ci * 100;
                int rr = rem / 10, cc = rem - rr * 10;
                xlds[i] = xb[(size_t)(cig * 16 + ci) * (HX * WX) + rr * WX + cc];
            }
        }
        __syncthreads();
        #pragma unroll
        for (int jj = 0; jj < 36; ++jj) {
            int col = acq * 36 + jj;
            int ci = (col * 57) >> 9;     // /9
            int kk = col - ci * 9;
            int ky = kk / 3, kx = kk - ky * 3;
            alds[aoff192(apx, col)] =
                f2bf(xlds[ci * 100 + (py + ky) * 10 + (pxx + kx)]);
        }
        __syncthreads();
        int arow = w * 16 + lm;
        const unsigned short* bbase = w0b + (size_t)cig * 64 * 160;
        #pragma unroll
        for (int ks = 0; ks < 5; ++ks) {
            bf16x8 a = *(const bf16x8*)&alds[aoff192(arow, ks * 32 + lq * 8)];
            #pragma unroll
            for (int n = 0; n < 4; ++n) {
                bf16x8 bb = *(const bf16x8*)(bbase + (size_t)(n * 16 + lm) * 160
                                             + ks * 32 + lq * 8);
                acc[n] = __builtin_amdgcn_mfma_f32_16x16x32_bf16(a, bb, acc[n], 0, 0, 0);
            }
        }
    }

    __syncthreads();
    float* dlds = (float*)alds;   // 64*65 floats
    #pragma unroll
    for (int n = 0; n < 4; ++n) {
        int oc = n * 16 + lm;
        #pragma unroll
        for (int r = 0; r < 4; ++r) {
            int px = w * 16 + lq * 4 + r;
            dlds[oc * 65 + px] = acc[n][r];
        }
    }
    __syncthreads();
    {
        int oc = tid >> 2;
        int ppy = tid & 3;
        float bo = b0[oc];
        float4 o4;
        #pragma unroll
        for (int ppx = 0; ppx < 4; ++ppx) {
            const float* dp = &dlds[oc * 65 + (2 * ppy) * 8 + 2 * ppx];
            float m = fmaxf(fmaxf(dp[0], dp[1]), fmaxf(dp[8], dp[9])) + bo;
            ((float*)&o4)[ppx] = m;
        }
        *(float4*)(p1 + (((size_t)b * 64 + oc) * 64 + ty * 4 + ppy) * 64 + tx * 4) = o4;
    }
}

// ---------------- K2: FUSED 1x1 (64->32) + 3x3 pad=1 (32->32) -> t3
// grid 256 = b(4) * ty(8) * tx(8); block 256 = 4 waves. (round-7 proven)
__global__ __launch_bounds__(256) void k_conv13(const float* __restrict__ p1,
                                                const unsigned short* __restrict__ w1b,
                                                const float* __restrict__ b1,
                                                const unsigned short* __restrict__ w2b,
                                                const float* __restrict__ b2,
                                                float* __restrict__ t3) {
    int blk = blockIdx.x;
    int tx = blk & 7;
    int ty = (blk >> 3) & 7;
    int b = blk >> 6;
    int tid = threadIdx.x;
    int w = tid >> 6;
    int lane = tid & 63;
    int lm = lane & 15;
    int lq = lane >> 4;
    int oy0 = ty * 8, ox0 = tx * 8;

    __shared__ __align__(16) float t2b[32 * 100];            // 12800 B
    __shared__ __align__(16) unsigned short areg[64 * 192];  // 24576 B (A1/A3/dlds)

    // ---- step 1: stage p1 halo -> A1 bf16 [px100][ci64] (zero-padded)
    const float* pb = p1 + (size_t)(b * 64) * 4096;
    #pragma unroll
    for (int j = 0; j < 25; ++j) {
        int i = tid + j * 256;        // 0..6399
        int ci = i / 100;
        int pp = i - ci * 100;
        int rr = pp / 10, cc = pp - rr * 10;
        int gy = oy0 + rr - 1, gx = ox0 + cc - 1;
        bool ok = (gy >= 0) & (gy < 64) & (gx >= 0) & (gx < 64);
        float v = ok ? pb[(size_t)ci * 4096 + gy * 64 + gx] : 0.f;
        areg[aoff80(pp, ci)] = f2bf(v);
    }
    __syncthreads();

    // ---- step 2: 1x1 MFMA. 7 row-tiles over 4 waves (w, w+4).
    #pragma unroll
    for (int s7 = 0; s7 < 2; ++s7) {
        int rt = w + s7 * 4;
        if (rt < 7) {
            f32x4 a1[2];
            a1[0] = (f32x4){0.f, 0.f, 0.f, 0.f};
            a1[1] = (f32x4){0.f, 0.f, 0.f, 0.f};
            #pragma unroll
            for (int ks = 0; ks < 2; ++ks) {
                bf16x8 a = *(const bf16x8*)&areg[aoff80(rt * 16 + lm, ks * 32 + lq * 8)];
                #pragma unroll
                for (int n = 0; n < 2; ++n) {
                    bf16x8 bb = *(const bf16x8*)(w1b + (size_t)(n * 16 + lm) * 64
                                                 + ks * 32 + lq * 8);
                    a1[n] = __builtin_amdgcn_mfma_f32_16x16x32_bf16(a, bb, a1[n], 0, 0, 0);
                }
            }
            #pragma unroll
            for (int n = 0; n < 2; ++n) {
                int oc = n * 16 + lm;
                float bv = b1[oc];
                #pragma unroll
                for (int r = 0; r < 4; ++r) {
                    int px = rt * 16 + lq * 4 + r;
                    if (px < 100) t2b[oc * 100 + px] = a1[n][r] + bv;
                }
            }
        }
    }
    __syncthreads();              // t2b complete; A1 dead

    // ---- steps 3/4: conv3 via 2 cig rounds on A3 [64px][144+16pad]
    int apx = tid >> 2, acq = tid & 3;
    int py = apx >> 3, pxx = apx & 7;
    f32x4 acc3[2];
    acc3[0] = (f32x4){0.f, 0.f, 0.f, 0.f};
    acc3[1] = (f32x4){0.f, 0.f, 0.f, 0.f};
    if (tid < 128) {              // zero pad cols 144..159 (after A1 reads done)
        *(bf16x8*)&areg[aoff192(tid >> 1, 144 + (tid & 1) * 8)] =
            (bf16x8){0, 0, 0, 0, 0, 0, 0, 0};
    }
    #pragma unroll 1
    for (int cig = 0; cig < 2; ++cig) {
        __syncthreads();          // pad visible (cig0) / prev MFMA reads done
        #pragma unroll
        for (int jj = 0; jj < 36; ++jj) {
            int col = acq * 36 + jj;
            int ci = (col * 57) >> 9;
            int kk = col - ci * 9;
            int ky = kk / 3, kx = kk - ky * 3;
            areg[aoff192(apx, col)] =
                f2bf(t2b[(cig * 16 + ci) * 100 + (py + ky) * 10 + (pxx + kx)]);
        }
        __syncthreads();
        int arow = w * 16 + lm;
        const unsigned short* bbase = w2b + (size_t)cig * 32 * 160;
        #pragma unroll
        for (int ks = 0; ks < 5; ++ks) {
            bf16x8 a = *(const bf16x8*)&areg[aoff192(arow, ks * 32 + lq * 8)];
            #pragma unroll
            for (int n = 0; n < 2; ++n) {
                bf16x8 bb = *(const bf16x8*)(bbase + (size_t)(n * 16 + lm) * 160
                                             + ks * 32 + lq * 8);
                acc3[n] = __builtin_amdgcn_mfma_f32_16x16x32_bf16(a, bb, acc3[n], 0, 0, 0);
            }
        }
    }

    // ---- epilogue: D[64px][32oc] -> LDS -> bias -> t3
    __syncthreads();
    float* dlds = (float*)areg;   // 32*65 floats = 8320 B
    #pragma unroll
    for (int n = 0; n < 2; ++n) {
        int oc = n * 16 + lm;
        #pragma unroll
        for (int r = 0; r < 4; ++r) {
            int px = w * 16 + lq * 4 + r;
            dlds[oc * 65 + px] = acc3[n][r];
        }
    }
    __syncthreads();
    {
        int oc = tid >> 3;        // 0..31
        int r = tid & 7;
        float bo = b2[oc];
        const float* dp = &dlds[oc * 65 + r * 8];
        float* op = t3 + ((size_t)(b * 32 + oc) * 64 + oy0 + r) * 64 + ox0;
        float4 a4 = make_float4(dp[0] + bo, dp[1] + bo, dp[2] + bo, dp[3] + bo);
        float4 b4 = make_float4(dp[4] + bo, dp[5] + bo, dp[6] + bo, dp[7] + bo);
        *(float4*)(op) = a4;
        *(float4*)(op + 4) = b4;
    }
}

// ---------------- K5: deformable conv (v5 body + gather ILP batching)
// grid 1024, XCD batch-clustered swizzle (neutral, kept). Per sub-phase:
// 18 f16-MFMA offset tiles -> soff; gathers in 3 groups of 3 (loads issued
// batch-first into Ld[3][6] regs); 9x4 bf16-MFMA phase-2 with setprio.
__global__ __launch_bounds__(256, 3) void k_deform(const float* __restrict__ x,
                                                   const float* __restrict__ t3,
                                                   const __half* __restrict__ w3h,
                                                   const float* __restrict__ b3,
                                                   const unsigned short* __restrict__ wdtb,
                                                   float* __restrict__ out) {
    int blk = blockIdx.x;
    int k8 = blk & 7;             // XCD (dispatch round-robin heuristic)
    int j8 = blk >> 3;            // 0..127
    int b = k8 & 3;               // batch clustered per XCD
    int strip = j8 * 2 + (k8 >> 2);   // 0..255, bijective
    int tid = threadIdx.x;
    int po0 = strip * 16;
    int qy = po0 >> 6;            // strip lies in one quad-row
    int qx0 = po0 & 63;
    int w = tid >> 6;             // wave id
    int lane = tid & 63;
    int lm = lane & 15;
    int lq = lane >> 4;
    int tq = tid & 15;            // pooled-px column this thread serves (fixed)
    int kb = tid >> 4;            // kcol = it*16 + kb

    __shared__ __align__(16) unsigned short alds[64 * 320];   // 40960 B
    __shared__ __align__(16) __half2 soff[2304];              //  9216 B
    __shared__ __align__(16) _Float16 st3t[16 * 40];          //  1280 B

    f32x4 acc[4];
    #pragma unroll
    for (int n = 0; n < 4; ++n) acc[n] = (f32x4){0.f, 0.f, 0.f, 0.f};

    const float* xb = x + (size_t)b * 64 * HX * WX;
    float fybase = (float)(2 * qy);
    float fxbase = (float)(2 * (qx0 + tq));

    // ---- stage t3 tile (32 ci x 16 px) to LDS as fp16, px-major pitch 40
    {
        int px = tid & 15, ci0 = tid >> 4;    // ci0 0..15
        const float* t3p = t3 + (size_t)b * 32 * 4096 + (qy * 64 + qx0 + px);
        st3t[px * 40 + ci0]      = (_Float16)t3p[(size_t)ci0 * 4096];
        st3t[px * 40 + ci0 + 16] = (_Float16)t3p[(size_t)(ci0 + 16) * 4096];
    }
    __syncthreads();
    // B-frag (t3) for the offset MFMA: lane holds t3[px=lm][ci=lq*8+j].
    const f16x8 bfrag = *(const f16x8*)&st3t[lm * 40 + lq * 8];

    for (int h = 0; h < 2; ++h) {
        #pragma unroll 1
        for (int sl = 0; sl < 2; ++sl) {
            int s = h * 2 + sl;           // sup = 16 channels
            __syncthreads();              // alds+soff free (prev phase done)

            // ---- phase 1a: offsets via f16 MFMA. 18 tiles of 16 off-ch.
            #pragma unroll
            for (int rep = 0; rep < 5; ++rep) {
                int t = rep * 4 + w;
                if (rep == 4) { if (w >= 2) break; t = 16 + w; }
                const f16x8 afrag = *(const f16x8*)((const _Float16*)w3h
                        + (size_t)(s * 288 + t * 16 + lm) * 32 + lq * 8);
                f32x4 d = __builtin_amdgcn_mfma_f32_16x16x32_f16(
                        afrag, bfrag, (f32x4){0.f, 0.f, 0.f, 0.f}, 0, 0, 0);
                float4 bq = *(const float4*)(b3 + s * 288 + t * 16 + lq * 4);
                int p0 = (t * 8 + lq * 2) * 16 + lm;   // pair-slot kcol*16+px
                soff[p0]      = __floats2half2_rn(d[0] + bq.x, d[1] + bq.y);
                soff[p0 + 16] = __floats2half2_rn(d[2] + bq.z, d[3] + bq.w);
            }
            __syncthreads();              // soff visible

            // ---- phase 1b: prefetch 9 offset pairs (word = it*256 + tid)
            __half2 o2h[9];
            #pragma unroll
            for (int it = 0; it < 9; ++it)
                o2h[it] = soff[it * 256 + tid];
            // gather: 3 groups of 3 tasks; loads issued batch-first (ILP)
            #pragma unroll 1
            for (int g = 0; g < 3; ++g) {
                float2 Ld[3][6];
                float fxv[3], fyv[3];
                int clv[3], oddv[3], y0v[3], x0v[3];
                const float* xpv[3];
                bool fastv[3];
                #pragma unroll
                for (int u = 0; u < 3; ++u) {
                    int it = g * 3 + u;
                    int kcol = it * 16 + kb;      // 0..143
                    int lc = kcol >= 72;
                    int ckk = kcol - 72 * lc;     // 0..71
                    int ch = (ckk * 57) >> 9;     // /9
                    int kk = ckk - ch * 9;
                    int c = s * 16 + lc * 8 + ch;
                    clv[u] = sl * 144 + kcol;     // A column 0..287
                    float2 off = __half22float2(o2h[it]);
                    float py = off.x + fybase + (float)(kk / 3);
                    float px = off.y + fxbase + (float)(kk % 3);
                    float y0f = floorf(py), x0f = floorf(px);
                    fyv[u] = py - y0f;
                    fxv[u] = px - x0f;
                    int y0 = (int)y0f, x0 = (int)x0f;
                    const float* xp = xb + (size_t)c * (HX * WX);
                    xpv[u] = xp; y0v[u] = y0; x0v[u] = x0;
                    bool fastok = (y0 >= 0) & (y0 <= HX - 3) & (x0 >= 0) & (x0 <= WX - 3);
                    fastv[u] = __all(fastok);
                    if (fastv[u]) {
                        oddv[u] = x0 & 1;
                        const float* rp = xp + y0 * WX + (x0 & ~1);
                        #pragma unroll
                        for (int r = 0; r < 3; ++r) {
                            Ld[u][2 * r]     = *(const float2*)(rp);
                            Ld[u][2 * r + 1] = *(const float2*)(rp + 2);
                            rp += WX;
                        }
                    }
                }
                #pragma unroll
                for (int u = 0; u < 3; ++u) {
                    float tv[3][3];
                    if (fastv[u]) {
                        int odd = oddv[u];
                        #pragma unroll
                        for (int r = 0; r < 3; ++r) {
                            float2 A = Ld[u][2 * r];
                            float2 B = Ld[u][2 * r + 1];
                            tv[r][0] = odd ? A.y : A.x;
                            tv[r][1] = odd ? B.x : A.y;
                            tv[r][2] = odd ? B.y : B.x;
                        }
                    } else {
                        int y0 = y0v[u], x0 = x0v[u];
                        const float* xp = xpv[u];
                        #pragma unroll
                        for (int r = 0; r < 3; ++r) {
                            int yy = y0 + r;
                            bool vy = (yy >= 0) & (yy < HX);
                            int yc = min(max(yy, 0), HX - 1);
                            #pragma unroll
                            for (int sx = 0; sx < 3; ++sx) {
                                int xx = x0 + sx;
                                bool vx = (xx >= 0) & (xx < WX);
                                int xc = min(max(xx, 0), WX - 1);
                                float val = xp[yc * WX + xc];
                                tv[r][sx] = (vy & vx) ? val : 0.f;
                            }
                        }
                    }
                    float fx = fxv[u], fy = fyv[u];
                    float h0[3], h1[3];
                    #pragma unroll
                    for (int r = 0; r < 3; ++r) {
                        h0[r] = tv[r][0] + fx * (tv[r][1] - tv[r][0]);
                        h1[r] = tv[r][1] + fx * (tv[r][2] - tv[r][1]);
                    }
                    int clocal = clv[u];
                    alds[aoff320(0 * 16 + tq, clocal)] = f2bf(h0[0] + fy * (h0[1] - h0[0]));
                    alds[aoff320(1 * 16 + tq, clocal)] = f2bf(h1[0] + fy * (h1[1] - h1[0]));
                    alds[aoff320(2 * 16 + tq, clocal)] = f2bf(h0[1] + fy * (h0[2] - h0[1]));
                    alds[aoff320(3 * 16 + tq, clocal)] = f2bf(h1[1] + fy * (h1[2] - h1[1]));
                }
            }
        }
        __syncthreads();          // A-tile (288 cols) visible

        // ---- phase 2: D[64px][64oc] += V[64][288] . W^T  (MFMA bf16)
        int arow = w * 16 + lm;
        const unsigned short* bbase = wdtb + (size_t)(h * 64) * 288;
        __builtin_amdgcn_s_setprio(1);
        #pragma unroll
        for (int ks = 0; ks < 9; ++ks) {
            bf16x8 a = *(const bf16x8*)&alds[aoff320(arow, ks * 32 + lq * 8)];
            #pragma unroll
            for (int n = 0; n < 4; ++n) {
                bf16x8 bb = *(const bf16x8*)(bbase + (size_t)(n * 16 + lm) * 288
                                             + ks * 32 + lq * 8);
                acc[n] = __builtin_amdgcn_mfma_f32_16x16x32_bf16(a, bb, acc[n], 0, 0, 0);
            }
        }
        __builtin_amdgcn_s_setprio(0);
    }

    // ---- epilogue via LDS: D lane layout -> [oc][px] -> coalesced stores
    __syncthreads();              // all phase-2 reads of alds complete
    float* dlds = (float*)alds;   // 64*65 = 4160 floats
    #pragma unroll
    for (int n = 0; n < 4; ++n) {
        int oc = n * 16 + lm;
        #pragma unroll
        for (int r = 0; r < 4; ++r) {
            int px = w * 16 + lq * 4 + r;     // = sub*16 + q
            dlds[oc * 65 + px] = acc[n][r];
        }
    }
    __syncthreads();
    {
        int oc = tid >> 2;
        int sy = (tid >> 1) & 1;
        int qh = (tid & 1) * 8;
        float* orow = out + (((size_t)b * 64 + oc) * 128 + 2 * qy + sy) * 128 + 2 * qx0;
        const float* d0 = &dlds[oc * 65 + (sy * 2 + 0) * 16];
        const float* d1 = &dlds[oc * 65 + (sy * 2 + 1) * 16];
        #pragma unroll
        for (int i = 0; i < 8; ++i) {
            int q = qh + i;
            *(float2*)(orow + 2 * q) = make_float2(d0[q], d1[q]);
        }
    }
}

extern "C" void kernel_launch(void* const* d_in, const int* in_sizes, int n_in,
                              void* d_out, int out_size, void* d_ws, size_t ws_size,
                              hipStream_t stream) {
    const float* x  = (const float*)d_in[0];
    const float* w0 = (const float*)d_in[1];
    const float* b0 = (const float*)d_in[2];
    const float* w1 = (const float*)d_in[3];
    const float* b1 = (const float*)d_in[4];
    const float* w2 = (const float*)d_in[5];
    const float* b2 = (const float*)d_in[6];
    const float* w3 = (const float*)d_in[7];
    const float* b3 = (const float*)d_in[8];
    const float* wd = (const float*)d_in[9];
    float* out = (float*)d_out;

    float* ws = (float*)d_ws;
    float* p1    = ws;                       // 1,048,576 floats
    float* t3    = p1 + 1048576;             //   524,288
    unsigned short* wdtb = (unsigned short*)(t3 + 524288);  // 36,864 + 16 pad
    __half* w3h = (__half*)(wdtb + 36880);   // 36,864 fp16 (16B-aligned)
    unsigned short* w0b = (unsigned short*)(w3h + 36864);   // 40,960 bf16
    unsigned short* w2b = w0b + 40960;                      // 10,240 bf16
    unsigned short* w1b = w2b + 10240;                      //  2,048 bf16

    k_wdt<<<496, 256, 0, stream>>>(wd, w3, w0, w2, w1, wdtb, w3h, w0b, w2b, w1b);
    k_conv0_mfma<<<1024, 256, 0, stream>>>(x, w0b, b0, p1);
    k_conv13<<<256, 256, 0, stream>>>(p1, w1b, b1, w2b, b2, t3);
    k_deform<<<1024, 256, 0, stream>>>(x, t3, w3h, b3, wdtb, out);
}

// Round 11
// 229.498 us; speedup vs baseline: 1.0352x; 1.0352x over previous
//
#include <hip/hip_runtime.h>
#include <hip/hip_bf16.h>
#include <hip/hip_fp16.h>

// Pipeline:
//  x (4,64,130,130) --conv3x3 valid + bias + maxpool2x2 (MFMA)--> p1 (4,64,64,64)
//  p1 --[FUSED k_conv13: 1x1 (64->32) MFMA in LDS + 3x3 pad=1 MFMA]--> t3
//  [FUSED] offset conv (32->1152) computed INSIDE k_deform via f16 MFMA
//  deform_conv(x, upsample2x(offsets), wd) -> out (4,64,128,128)
//
//  Round-11: round-10 structure with the shfl-select bug FIXED.
//   - Round-10 selected d[2*(k8&1)] BEFORE the shuffle; __shfl returns the
//     SOURCE lane's value of that expression, and source lane lq*16+tq has
//     odd_k=lq&1 != consumer's k8&1 for k8 in {1,2} mod 4 -> half the
//     offsets wrong (absmax 1.48). Fix: shuffle all 4 D regs, select AFTER
//     (consumer-side odd_k applied to source data). 4 shfls/task, free.
//   - Rest unchanged: per-wave offset MFMA (tile t=2it+tpar), barrier-free
//     phase-1 (2 barriers/half instead of v5's 10 total), soff deleted,
//     offsets fp32. Conv kernels + k_wdt = round-8 proven.
//   - WRITE_SIZE==16.4MB is the spill sentinel; dur>=84us kills the theory.

#define HX 130
#define WX 130

typedef short bf16x8 __attribute__((ext_vector_type(8)));
typedef _Float16 f16x8 __attribute__((ext_vector_type(8)));
typedef float f32x4 __attribute__((ext_vector_type(4)));

static __device__ __forceinline__ unsigned short f2bf(float f) {
    unsigned u = __float_as_uint(f);
    unsigned r = u + 0x7fff + ((u >> 16) & 1);   // round-to-nearest-even
    return (unsigned short)(r >> 16);
}

// A-tile address (in shorts): row pitch 320, 16B-block swizzle (k_deform v5)
static __device__ __forceinline__ int aoff320(int row, int col) {
    return row * 320 + ((((col >> 3) ^ (row & 7))) << 3) + (col & 7);
}

// A-tile address (in shorts): row pitch 192 (160-col tiles), 16B-block swizzle
static __device__ __forceinline__ int aoff192(int row, int col) {
    return row * 192 + ((((col >> 3) ^ (row & 7))) << 3) + (col & 7);
}

// A-tile address (in shorts): row pitch 80 (64-col 1x1 tile), same family
static __device__ __forceinline__ int aoff80(int row, int col) {
    return row * 80 + ((((col >> 3) ^ (row & 7))) << 3) + (col & 7);
}

// ---------------- K0: weight prep
//  idx <  36864 : wd -> bf16 wdtb[h(2)][oc(64)][col(288)]  (+16 zero tail)
//  idx <  73728 : w3 -> fp16 w3h[1152][32]
//  idx < 114688 : w0 -> bf16 w0b[cig(4)][oc(64)][160]; col=ci_l*9+kk, pad 0
//  idx < 124928 : w2 -> bf16 w2b[cig(2)][oc(32)][160]; col=ci_l*9+kk, pad 0
//  idx < 126976 : w1 -> bf16 w1b[oc(32)][64] (contiguous copy-convert)
__global__ __launch_bounds__(256) void k_wdt(const float* __restrict__ wd,
                                             const float* __restrict__ w3,
                                             const float* __restrict__ w0,
                                             const float* __restrict__ w2,
                                             const float* __restrict__ w1,
                                             unsigned short* __restrict__ wdtb,
                                             __half* __restrict__ w3h,
                                             unsigned short* __restrict__ w0b,
                                             unsigned short* __restrict__ w2b,
                                             unsigned short* __restrict__ w1b) {
    int idx = blockIdx.x * 256 + threadIdx.x;   // grid 496*256 = 126976
    if (idx < 36864) {
        int o = idx / 576;
        int rem = idx - o * 576;
        int c = rem / 9;
        int kk = rem - c * 9;
        int h = c >> 5;
        int c5 = c & 31;
        int col = (c5 >> 4) * 144 + ((c5 >> 3) & 1) * 72 + (c5 & 7) * 9 + kk;
        wdtb[(size_t)(h * 64 + o) * 288 + col] = f2bf(wd[idx]);
        if (idx < 16) wdtb[36864 + idx] = 0;    // tail pad: guard 0*NaN
    } else if (idx < 73728) {
        int i2 = idx - 36864;
        w3h[i2] = __float2half_rn(w3[i2]);
    } else if (idx < 114688) {
        int i3 = idx - 73728;                   // 0..40959
        int row = i3 / 160;                     // cig*64 + oc
        int col = i3 - row * 160;
        int cig = row >> 6, oc = row & 63;
        unsigned short v = 0;
        if (col < 144) {
            int ci = (col * 57) >> 9;           // /9, valid col<144
            int kk = col - ci * 9;
            v = f2bf(w0[(size_t)(oc * 64 + cig * 16 + ci) * 9 + kk]);
        }
        w0b[i3] = v;
    } else if (idx < 124928) {
        int i4 = idx - 114688;                  // 0..10239
        int row = i4 / 160;                     // cig*32 + oc
        int col = i4 - row * 160;
        int cig = row >> 5, oc = row & 31;
        unsigned short v = 0;
        if (col < 144) {
            int ci = (col * 57) >> 9;
            int kk = col - ci * 9;
            v = f2bf(w2[(size_t)(oc * 32 + cig * 16 + ci) * 9 + kk]);
        }
        w2b[i4] = v;
    } else {
        int i5 = idx - 124928;                  // 0..2047
        w1b[i5] = f2bf(w1[i5]);
    }
}

// ---------------- K1: conv3x3 valid (64->64) via MFMA + bias + maxpool -> p1
// grid 1024 = b(4) * ty(16) * tx(16); block 256 = 4 waves. (round-5 proven)
__global__ __launch_bounds__(256, 4) void k_conv0_mfma(const float* __restrict__ x,
                                                       const unsigned short* __restrict__ w0b,
                                                       const float* __restrict__ b0,
                                                       float* __restrict__ p1) {
    int blk = blockIdx.x;
    int tx = blk & 15;
    int ty = (blk >> 4) & 15;
    int b = blk >> 8;
    int tid = threadIdx.x;
    int w = tid >> 6;
    int lane = tid & 63;
    int lm = lane & 15;
    int lq = lane >> 4;
    int oy0 = ty * 8, ox0 = tx * 8;

    __shared__ __align__(16) unsigned short alds[64 * 192];   // 24576 B
    __shared__ __align__(16) float xlds[1600];                //  6400 B

    f32x4 acc[4];
    #pragma unroll
    for (int n = 0; n < 4; ++n) acc[n] = (f32x4){0.f, 0.f, 0.f, 0.f};

    if (tid < 128) {
        *(bf16x8*)&alds[aoff192(tid >> 1, 144 + (tid & 1) * 8)] =
            (bf16x8){0, 0, 0, 0, 0, 0, 0, 0};
    }

    const float* xb = x + (size_t)(b * 64) * (HX * WX) + oy0 * WX + ox0;
    int apx = tid >> 2;           // 0..63 conv px (py*8+pxx)
    int acq = tid & 3;            // col slice
    int py = apx >> 3, pxx = apx & 7;

    for (int cig = 0; cig < 4; ++cig) {
        #pragma unroll
        for (int j = 0; j < 7; ++j) {
            int i = tid + j * 256;
            if (i < 1600) {
                int ci = i / 100;
                int rem = i - ci * 100;
                int rr = rem / 10, cc = rem - rr * 10;
                xlds[i] = xb[(size_t)(cig * 16 + ci) * (HX * WX) + rr * WX + cc];
            }
        }
        __syncthreads();
        #pragma unroll
        for (int jj = 0; jj < 36; ++jj) {
            int col = acq * 36 + jj;
            int ci = (col * 57) >> 9;     // /9
            int kk = col - ci * 9;
            int ky = kk / 3, kx = kk - ky * 3;
            alds[aoff192(apx, col)] =
                f2bf(xlds[ci * 100 + (py + ky) * 10 + (pxx + kx)]);
        }
        __syncthreads();
        int arow = w * 16 + lm;
        const unsigned short* bbase = w0b + (size_t)cig * 64 * 160;
        #pragma unroll
        for (int ks = 0; ks < 5; ++ks) {
            bf16x8 a = *(const bf16x8*)&alds[aoff192(arow, ks * 32 + lq * 8)];
            #pragma unroll
            for (int n = 0; n < 4; ++n) {
                bf16x8 bb = *(const bf16x8*)(bbase + (size_t)(n * 16 + lm) * 160
                                             + ks * 32 + lq * 8);
                acc[n] = __builtin_amdgcn_mfma_f32_16x16x32_bf16(a, bb, acc[n], 0, 0, 0);
            }
        }
    }

    __syncthreads();
    float* dlds = (float*)alds;   // 64*65 floats
    #pragma unroll
    for (int n = 0; n < 4; ++n) {
        int oc = n * 16 + lm;
        #pragma unroll
        for (int r = 0; r < 4; ++r) {
            int px = w * 16 + lq * 4 + r;
            dlds[oc * 65 + px] = acc[n][r];
        }
    }
    __syncthreads();
    {
        int oc = tid >> 2;
        int ppy = tid & 3;
        float bo = b0[oc];
        float4 o4;
        #pragma unroll
        for (int ppx = 0; ppx < 4; ++ppx) {
            const float* dp = &dlds[oc * 65 + (2 * ppy) * 8 + 2 * ppx];
            float m = fmaxf(fmaxf(dp[0], dp[1]), fmaxf(dp[8], dp[9])) + bo;
            ((float*)&o4)[ppx] = m;
        }
        *(float4*)(p1 + (((size_t)b * 64 + oc) * 64 + ty * 4 + ppy) * 64 + tx * 4) = o4;
    }
}

// ---------------- K2: FUSED 1x1 (64->32) + 3x3 pad=1 (32->32) -> t3
// grid 256 = b(4) * ty(8) * tx(8); block 256 = 4 waves. (round-7 proven)
__global__ __launch_bounds__(256) void k_conv13(const float* __restrict__ p1,
                                                const unsigned short* __restrict__ w1b,
                                                const float* __restrict__ b1,
                                                const unsigned short* __restrict__ w2b,
                                                const float* __restrict__ b2,
                                                float* __restrict__ t3) {
    int blk = blockIdx.x;
    int tx = blk & 7;
    int ty = (blk >> 3) & 7;
    int b = blk >> 6;
    int tid = threadIdx.x;
    int w = tid >> 6;
    int lane = tid & 63;
    int lm = lane & 15;
    int lq = lane >> 4;
    int oy0 = ty * 8, ox0 = tx * 8;

    __shared__ __align__(16) float t2b[32 * 100];            // 12800 B
    __shared__ __align__(16) unsigned short areg[64 * 192];  // 24576 B (A1/A3/dlds)

    // ---- step 1: stage p1 halo -> A1 bf16 [px100][ci64] (zero-padded)
    const float* pb = p1 + (size_t)(b * 64) * 4096;
    #pragma unroll
    for (int j = 0; j < 25; ++j) {
        int i = tid + j * 256;        // 0..6399
        int ci = i / 100;
        int pp = i - ci * 100;
        int rr = pp / 10, cc = pp - rr * 10;
        int gy = oy0 + rr - 1, gx = ox0 + cc - 1;
        bool ok = (gy >= 0) & (gy < 64) & (gx >= 0) & (gx < 64);
        float v = ok ? pb[(size_t)ci * 4096 + gy * 64 + gx] : 0.f;
        areg[aoff80(pp, ci)] = f2bf(v);
    }
    __syncthreads();

    // ---- step 2: 1x1 MFMA. 7 row-tiles over 4 waves (w, w+4).
    #pragma unroll
    for (int s7 = 0; s7 < 2; ++s7) {
        int rt = w + s7 * 4;
        if (rt < 7) {
            f32x4 a1[2];
            a1[0] = (f32x4){0.f, 0.f, 0.f, 0.f};
            a1[1] = (f32x4){0.f, 0.f, 0.f, 0.f};
            #pragma unroll
            for (int ks = 0; ks < 2; ++ks) {
                bf16x8 a = *(const bf16x8*)&areg[aoff80(rt * 16 + lm, ks * 32 + lq * 8)];
                #pragma unroll
                for (int n = 0; n < 2; ++n) {
                    bf16x8 bb = *(const bf16x8*)(w1b + (size_t)(n * 16 + lm) * 64
                                                 + ks * 32 + lq * 8);
                    a1[n] = __builtin_amdgcn_mfma_f32_16x16x32_bf16(a, bb, a1[n], 0, 0, 0);
                }
            }
            #pragma unroll
            for (int n = 0; n < 2; ++n) {
                int oc = n * 16 + lm;
                float bv = b1[oc];
                #pragma unroll
                for (int r = 0; r < 4; ++r) {
                    int px = rt * 16 + lq * 4 + r;
                    if (px < 100) t2b[oc * 100 + px] = a1[n][r] + bv;
                }
            }
        }
    }
    __syncthreads();              // t2b complete; A1 dead

    // ---- steps 3/4: conv3 via 2 cig rounds on A3 [64px][144+16pad]
    int apx = tid >> 2, acq = tid & 3;
    int py = apx >> 3, pxx = apx & 7;
    f32x4 acc3[2];
    acc3[0] = (f32x4){0.f, 0.f, 0.f, 0.f};
    acc3[1] = (f32x4){0.f, 0.f, 0.f, 0.f};
    if (tid < 128) {              // zero pad cols 144..159 (after A1 reads done)
        *(bf16x8*)&areg[aoff192(tid >> 1, 144 + (tid & 1) * 8)] =
            (bf16x8){0, 0, 0, 0, 0, 0, 0, 0};
    }
    #pragma unroll 1
    for (int cig = 0; cig < 2; ++cig) {
        __syncthreads();          // pad visible (cig0) / prev MFMA reads done
        #pragma unroll
        for (int jj = 0; jj < 36; ++jj) {
            int col = acq * 36 + jj;
            int ci = (col * 57) >> 9;
            int kk = col - ci * 9;
            int ky = kk / 3, kx = kk - ky * 3;
            areg[aoff192(apx, col)] =
                f2bf(t2b[(cig * 16 + ci) * 100 + (py + ky) * 10 + (pxx + kx)]);
        }
        __syncthreads();
        int arow = w * 16 + lm;
        const unsigned short* bbase = w2b + (size_t)cig * 32 * 160;
        #pragma unroll
        for (int ks = 0; ks < 5; ++ks) {
            bf16x8 a = *(const bf16x8*)&areg[aoff192(arow, ks * 32 + lq * 8)];
            #pragma unroll
            for (int n = 0; n < 2; ++n) {
                bf16x8 bb = *(const bf16x8*)(bbase + (size_t)(n * 16 + lm) * 160
                                             + ks * 32 + lq * 8);
                acc3[n] = __builtin_amdgcn_mfma_f32_16x16x32_bf16(a, bb, acc3[n], 0, 0, 0);
            }
        }
    }

    // ---- epilogue: D[64px][32oc] -> LDS -> bias -> t3
    __syncthreads();
    float* dlds = (float*)areg;   // 32*65 floats = 8320 B
    #pragma unroll
    for (int n = 0; n < 2; ++n) {
        int oc = n * 16 + lm;
        #pragma unroll
        for (int r = 0; r < 4; ++r) {
            int px = w * 16 + lq * 4 + r;
            dlds[oc * 65 + px] = acc3[n][r];
        }
    }
    __syncthreads();
    {
        int oc = tid >> 3;        // 0..31
        int r = tid & 7;
        float bo = b2[oc];
        const float* dp = &dlds[oc * 65 + r * 8];
        float* op = t3 + ((size_t)(b * 32 + oc) * 64 + oy0 + r) * 64 + ox0;
        float4 a4 = make_float4(dp[0] + bo, dp[1] + bo, dp[2] + bo, dp[3] + bo);
        float4 b4 = make_float4(dp[4] + bo, dp[5] + bo, dp[6] + bo, dp[7] + bo);
        *(float4*)(op) = a4;
        *(float4*)(op + 4) = b4;
    }
}

// ---------------- K5: deformable conv, per-wave-offset barrier-free phase-1
// grid 1024, XCD batch-clustered swizzle. Per sub-phase each wave computes
// its own 9 offset tiles (t = 2*it + tpar); thread (kb,tq) extracts (py,px)
// via 4 static-lane shfls + consumer-side select (round-10 bugfix); gather
// -> A-tile. 2 barriers per half.
__global__ __launch_bounds__(256, 3) void k_deform(const float* __restrict__ x,
                                                   const float* __restrict__ t3,
                                                   const __half* __restrict__ w3h,
                                                   const float* __restrict__ b3,
                                                   const unsigned short* __restrict__ wdtb,
                                                   float* __restrict__ out) {
    int blk = blockIdx.x;
    int k8x = blk & 7;            // XCD (dispatch round-robin heuristic)
    int j8 = blk >> 3;            // 0..127
    int b = k8x & 3;              // batch clustered per XCD
    int strip = j8 * 2 + (k8x >> 2);  // 0..255, bijective
    int tid = threadIdx.x;
    int po0 = strip * 16;
    int qy = po0 >> 6;            // strip lies in one quad-row
    int qx0 = po0 & 63;
    int w = tid >> 6;             // wave id
    int lane = tid & 63;
    int lm = lane & 15;
    int lq = lane >> 4;
    int tq = tid & 15;            // pooled-px column this thread serves (fixed)
    int kb = tid >> 4;            // kcol = it*16 + kb

    __shared__ __align__(16) unsigned short alds[64 * 320];   // 40960 B
    __shared__ __align__(16) _Float16 st3t[16 * 40];          //  1280 B

    f32x4 acc[4];
    #pragma unroll
    for (int n = 0; n < 4; ++n) acc[n] = (f32x4){0.f, 0.f, 0.f, 0.f};

    const float* xb = x + (size_t)b * 64 * HX * WX;
    float fybase = (float)(2 * qy);
    float fxbase = (float)(2 * (qx0 + tq));

    // offset-extraction constants (from proven D-layout: row=lq*4+r=off-ch,
    // col=lm=px): pair k8=kb&7 lives at lane (k8>>1)*16+tq; within that
    // lane's D, regs {2e,2e+1} with e=k8&1 hold (py,px). Select AFTER shfl.
    int k8 = kb & 7;
    int srcl = ((k8 >> 1) << 4) | tq;
    int odd_k = k8 & 1;
    int tpar = kb >> 3;           // tile parity: waves 0-1 even, 2-3 odd

    // ---- stage t3 tile (32 ci x 16 px) to LDS as fp16, px-major pitch 40
    {
        int px = tid & 15, ci0 = tid >> 4;    // ci0 0..15
        const float* t3p = t3 + (size_t)b * 32 * 4096 + (qy * 64 + qx0 + px);
        st3t[px * 40 + ci0]      = (_Float16)t3p[(size_t)ci0 * 4096];
        st3t[px * 40 + ci0 + 16] = (_Float16)t3p[(size_t)(ci0 + 16) * 4096];
    }
    __syncthreads();
    // B-frag (t3) for the offset MFMA: lane holds t3[px=lm][ci=lq*8+j].
    const f16x8 bfrag = *(const f16x8*)&st3t[lm * 40 + lq * 8];

    for (int h = 0; h < 2; ++h) {
        #pragma unroll 1
        for (int sl = 0; sl < 2; ++sl) {
            int s = h * 2 + sl;           // sup = 16 channels
            // ---- phase 1 (barrier-free): per-it {offset MFMA, shfl, gather}
            #pragma unroll
            for (int it = 0; it < 9; ++it) {
                int t = 2 * it + tpar;
                const f16x8 afrag = *(const f16x8*)((const _Float16*)w3h
                        + (size_t)(s * 288 + t * 16 + lm) * 32 + lq * 8);
                f32x4 d = __builtin_amdgcn_mfma_f32_16x16x32_f16(
                        afrag, bfrag, (f32x4){0.f, 0.f, 0.f, 0.f}, 0, 0, 0);
                // pull all 4 regs from source lane, select consumer-side
                float v0 = __shfl(d[0], srcl, 64);
                float v1 = __shfl(d[1], srcl, 64);
                float v2 = __shfl(d[2], srcl, 64);
                float v3 = __shfl(d[3], srcl, 64);
                float pyr = odd_k ? v2 : v0;
                float pxr = odd_k ? v3 : v1;
                int kcol = it * 16 + kb;      // 0..143
                float2 bq2 = *(const float2*)(b3 + s * 288 + 2 * kcol);
                int lc = kcol >= 72;
                int ckk = kcol - 72 * lc;     // 0..71
                int ch = (ckk * 57) >> 9;     // /9
                int kk = ckk - ch * 9;
                int c = s * 16 + lc * 8 + ch;
                int clocal = sl * 144 + kcol; // A column 0..287
                float py = pyr + bq2.x + fybase + (float)(kk / 3);
                float px = pxr + bq2.y + fxbase + (float)(kk % 3);
                float y0f = floorf(py), x0f = floorf(px);
                float fy = py - y0f, fx = px - x0f;
                int y0 = (int)y0f, x0 = (int)x0f;
                const float* xp = xb + (size_t)c * (HX * WX);
                float tv[3][3];
                bool fastok = (y0 >= 0) & (y0 <= HX - 3) & (x0 >= 0) & (x0 <= WX - 3);
                if (__all(fastok)) {
                    // whole wave in-bounds: even-aligned float2 pair per row
                    int xe = x0 & ~1;         // even -> 8B-aligned (WX even)
                    int odd = x0 & 1;
                    const float* rp = xp + y0 * WX + xe;
                    #pragma unroll
                    for (int r = 0; r < 3; ++r) {
                        float2 A = *(const float2*)(rp);
                        float2 B = *(const float2*)(rp + 2);
                        tv[r][0] = odd ? A.y : A.x;
                        tv[r][1] = odd ? B.x : A.y;
                        tv[r][2] = odd ? B.y : B.x;
                        rp += WX;
                    }
                } else {
                    #pragma unroll
                    for (int r = 0; r < 3; ++r) {
                        int yy = y0 + r;
                        bool vy = (yy >= 0) & (yy < HX);
                        int yc = min(max(yy, 0), HX - 1);
                        #pragma unroll
                        for (int sx = 0; sx < 3; ++sx) {
                            int xx = x0 + sx;
                            bool vx = (xx >= 0) & (xx < WX);
                            int xc = min(max(xx, 0), WX - 1);
                            float val = xp[yc * WX + xc];
                            tv[r][sx] = (vy & vx) ? val : 0.f;
                        }
                    }
                }
                float h0[3], h1[3];
                #pragma unroll
                for (int r = 0; r < 3; ++r) {
                    h0[r] = tv[r][0] + fx * (tv[r][1] - tv[r][0]);
                    h1[r] = tv[r][1] + fx * (tv[r][2] - tv[r][1]);
                }
                alds[aoff320(0 * 16 + tq, clocal)] = f2bf(h0[0] + fy * (h0[1] - h0[0]));
                alds[aoff320(1 * 16 + tq, clocal)] = f2bf(h1[0] + fy * (h1[1] - h1[0]));
                alds[aoff320(2 * 16 + tq, clocal)] = f2bf(h0[1] + fy * (h0[2] - h0[1]));
                alds[aoff320(3 * 16 + tq, clocal)] = f2bf(h1[1] + fy * (h1[2] - h1[1]));
            }
        }
        __syncthreads();          // A-tile (288 cols) visible

        // ---- phase 2: D[64px][64oc] += V[64][288] . W^T  (MFMA bf16)
        int arow = w * 16 + lm;
        const unsigned short* bbase = wdtb + (size_t)(h * 64) * 288;
        __builtin_amdgcn_s_setprio(1);
        #pragma unroll
        for (int ks = 0; ks < 9; ++ks) {
            bf16x8 a = *(const bf16x8*)&alds[aoff320(arow, ks * 32 + lq * 8)];
            #pragma unroll
            for (int n = 0; n < 4; ++n) {
                bf16x8 bb = *(const bf16x8*)(bbase + (size_t)(n * 16 + lm) * 288
                                             + ks * 32 + lq * 8);
                acc[n] = __builtin_amdgcn_mfma_f32_16x16x32_bf16(a, bb, acc[n], 0, 0, 0);
            }
        }
        __builtin_amdgcn_s_setprio(0);
        __syncthreads();          // alds free (next h gathers / epilogue)
    }

    // ---- epilogue via LDS: D lane layout -> [oc][px] -> coalesced stores
    float* dlds = (float*)alds;   // 64*65 = 4160 floats
    #pragma unroll
    for (int n = 0; n < 4; ++n) {
        int oc = n * 16 + lm;
        #pragma unroll
        for (int r = 0; r < 4; ++r) {
            int px = w * 16 + lq * 4 + r;     // = sub*16 + q
            dlds[oc * 65 + px] = acc[n][r];
        }
    }
    __syncthreads();
    {
        int oc = tid >> 2;
        int sy = (tid >> 1) & 1;
        int qh = (tid & 1) * 8;
        float* orow = out + (((size_t)b * 64 + oc) * 128 + 2 * qy + sy) * 128 + 2 * qx0;
        const float* d0 = &dlds[oc * 65 + (sy * 2 + 0) * 16];
        const float* d1 = &dlds[oc * 65 + (sy * 2 + 1) * 16];
        #pragma unroll
        for (int i = 0; i < 8; ++i) {
            int q = qh + i;
            *(float2*)(orow + 2 * q) = make_float2(d0[q], d1[q]);
        }
    }
}

extern "C" void kernel_launch(void* const* d_in, const int* in_sizes, int n_in,
                              void* d_out, int out_size, void* d_ws, size_t ws_size,
                              hipStream_t stream) {
    const float* x  = (const float*)d_in[0];
    const float* w0 = (const float*)d_in[1];
    const float* b0 = (const float*)d_in[2];
    const float* w1 = (const float*)d_in[3];
    const float* b1 = (const float*)d_in[4];
    const float* w2 = (const float*)d_in[5];
    const float* b2 = (const float*)d_in[6];
    const float* w3 = (const float*)d_in[7];
    const float* b3 = (const float*)d_in[8];
    const float* wd = (const float*)d_in[9];
    float* out = (float*)d_out;

    float* ws = (float*)d_ws;
    float* p1    = ws;                       // 1,048,576 floats
    float* t3    = p1 + 1048576;             //   524,288
    unsigned short* wdtb = (unsigned short*)(t3 + 524288);  // 36,864 + 16 pad
    __half* w3h = (__half*)(wdtb + 36880);   // 36,864 fp16 (16B-aligned)
    unsigned short* w0b = (unsigned short*)(w3h + 36864);   // 40,960 bf16
    unsigned short* w2b = w0b + 40960;                      // 10,240 bf16
    unsigned short* w1b = w2b + 10240;                      //  2,048 bf16

    k_wdt<<<496, 256, 0, stream>>>(wd, w3, w0, w2, w1, wdtb, w3h, w0b, w2b, w1b);
    k_conv0_mfma<<<1024, 256, 0, stream>>>(x, w0b, b0, p1);
    k_conv13<<<256, 256, 0, stream>>>(p1, w1b, b1, w2b, b2, t3);
    k_deform<<<1024, 256, 0, stream>>>(x, t3, w3h, b3, wdtb, out);
}

// Round 12
// 223.108 us; speedup vs baseline: 1.0649x; 1.0286x over previous
//
#include <hip/hip_runtime.h>
#include <hip/hip_bf16.h>
#include <hip/hip_fp16.h>

// Pipeline:
//  x (4,64,130,130) --conv3x3 valid + bias + maxpool2x2 (MFMA)--> p1 (4,64,64,64)
//  p1 --[FUSED k_conv13: 1x1 (64->32) MFMA in LDS + 3x3 pad=1 MFMA]--> t3
//  [FUSED] offset conv (32->1152) computed INSIDE k_deform via f16 MFMA
//  deform_conv(x, upsample2x(offsets), wd) -> out (4,64,128,128)
//
//  Round-12: REVERT to round-8 configuration (session best, 223.3 us).
//  k_deform structural ledger (7 variants): v5=84.1us floor; v6@(256,4)=94
//  (spill); v6@(256,3)=88.5 (barriers); +XCD/setprio=84.4 (null, kept:
//  free); ILP-batch=98.6 (spill); per-wave-offsets=90.5 (serial chain).
//  v5's batch-offsets->clean-gather-loop structure is what lets the
//  compiler overlap gather loads; every deviation regressed.

#define HX 130
#define WX 130

typedef short bf16x8 __attribute__((ext_vector_type(8)));
typedef _Float16 f16x8 __attribute__((ext_vector_type(8)));
typedef float f32x4 __attribute__((ext_vector_type(4)));

static __device__ __forceinline__ unsigned short f2bf(float f) {
    unsigned u = __float_as_uint(f);
    unsigned r = u + 0x7fff + ((u >> 16) & 1);   // round-to-nearest-even
    return (unsigned short)(r >> 16);
}

// A-tile address (in shorts): row pitch 320, 16B-block swizzle (k_deform v5)
static __device__ __forceinline__ int aoff320(int row, int col) {
    return row * 320 + ((((col >> 3) ^ (row & 7))) << 3) + (col & 7);
}

// A-tile address (in shorts): row pitch 192 (160-col tiles), 16B-block swizzle
static __device__ __forceinline__ int aoff192(int row, int col) {
    return row * 192 + ((((col >> 3) ^ (row & 7))) << 3) + (col & 7);
}

// A-tile address (in shorts): row pitch 80 (64-col 1x1 tile), same family
static __device__ __forceinline__ int aoff80(int row, int col) {
    return row * 80 + ((((col >> 3) ^ (row & 7))) << 3) + (col & 7);
}

// ---------------- K0: weight prep
//  idx <  36864 : wd -> bf16 wdtb[h(2)][oc(64)][col(288)]  (+16 zero tail)
//  idx <  73728 : w3 -> fp16 w3h[1152][32]
//  idx < 114688 : w0 -> bf16 w0b[cig(4)][oc(64)][160]; col=ci_l*9+kk, pad 0
//  idx < 124928 : w2 -> bf16 w2b[cig(2)][oc(32)][160]; col=ci_l*9+kk, pad 0
//  idx < 126976 : w1 -> bf16 w1b[oc(32)][64] (contiguous copy-convert)
__global__ __launch_bounds__(256) void k_wdt(const float* __restrict__ wd,
                                             const float* __restrict__ w3,
                                             const float* __restrict__ w0,
                                             const float* __restrict__ w2,
                                             const float* __restrict__ w1,
                                             unsigned short* __restrict__ wdtb,
                                             __half* __restrict__ w3h,
                                             unsigned short* __restrict__ w0b,
                                             unsigned short* __restrict__ w2b,
                                             unsigned short* __restrict__ w1b) {
    int idx = blockIdx.x * 256 + threadIdx.x;   // grid 496*256 = 126976
    if (idx < 36864) {
        int o = idx / 576;
        int rem = idx - o * 576;
        int c = rem / 9;
        int kk = rem - c * 9;
        int h = c >> 5;
        int c5 = c & 31;
        int col = (c5 >> 4) * 144 + ((c5 >> 3) & 1) * 72 + (c5 & 7) * 9 + kk;
        wdtb[(size_t)(h * 64 + o) * 288 + col] = f2bf(wd[idx]);
        if (idx < 16) wdtb[36864 + idx] = 0;    // tail pad: guard 0*NaN
    } else if (idx < 73728) {
        int i2 = idx - 36864;
        w3h[i2] = __float2half_rn(w3[i2]);
    } else if (idx < 114688) {
        int i3 = idx - 73728;                   // 0..40959
        int row = i3 / 160;                     // cig*64 + oc
        int col = i3 - row * 160;
        int cig = row >> 6, oc = row & 63;
        unsigned short v = 0;
        if (col < 144) {
            int ci = (col * 57) >> 9;           // /9, valid col<144
            int kk = col - ci * 9;
            v = f2bf(w0[(size_t)(oc * 64 + cig * 16 + ci) * 9 + kk]);
        }
        w0b[i3] = v;
    } else if (idx < 124928) {
        int i4 = idx - 114688;                  // 0..10239
        int row = i4 / 160;                     // cig*32 + oc
        int col = i4 - row * 160;
        int cig = row >> 5, oc = row & 31;
        unsigned short v = 0;
        if (col < 144) {
            int ci = (col * 57) >> 9;
            int kk = col - ci * 9;
            v = f2bf(w2[(size_t)(oc * 32 + cig * 16 + ci) * 9 + kk]);
        }
        w2b[i4] = v;
    } else {
        int i5 = idx - 124928;                  // 0..2047
        w1b[i5] = f2bf(w1[i5]);
    }
}

// ---------------- K1: conv3x3 valid (64->64) via MFMA + bias + maxpool -> p1
// grid 1024 = b(4) * ty(16) * tx(16); block 256 = 4 waves. (round-5 proven)
__global__ __launch_bounds__(256, 4) void k_conv0_mfma(const float* __restrict__ x,
                                                       const unsigned short* __restrict__ w0b,
                                                       const float* __restrict__ b0,
                                                       float* __restrict__ p1) {
    int blk = blockIdx.x;
    int tx = blk & 15;
    int ty = (blk >> 4) & 15;
    int b = blk >> 8;
    int tid = threadIdx.x;
    int w = tid >> 6;
    int lane = tid & 63;
    int lm = lane & 15;
    int lq = lane >> 4;
    int oy0 = ty * 8, ox0 = tx * 8;

    __shared__ __align__(16) unsigned short alds[64 * 192];   // 24576 B
    __shared__ __align__(16) float xlds[1600];                //  6400 B

    f32x4 acc[4];
    #pragma unroll
    for (int n = 0; n < 4; ++n) acc[n] = (f32x4){0.f, 0.f, 0.f, 0.f};

    if (tid < 128) {
        *(bf16x8*)&alds[aoff192(tid >> 1, 144 + (tid & 1) * 8)] =
            (bf16x8){0, 0, 0, 0, 0, 0, 0, 0};
    }

    const float* xb = x + (size_t)(b * 64) * (HX * WX) + oy0 * WX + ox0;
    int apx = tid >> 2;           // 0..63 conv px (py*8+pxx)
    int acq = tid & 3;            // col slice
    int py = apx >> 3, pxx = apx & 7;

    for (int cig = 0; cig < 4; ++cig) {
        #pragma unroll
        for (int j = 0; j < 7; ++j) {
            int i = tid + j * 256;
            if (i < 1600) {
                int ci = i / 100;
                int rem = i - ci * 100;
                int rr = rem / 10, cc = rem - rr * 10;
                xlds[i] = xb[(size_t)(cig * 16 + ci) * (HX * WX) + rr * WX + cc];
            }
        }
        __syncthreads();
        #pragma unroll
        for (int jj = 0; jj < 36; ++jj) {
            int col = acq * 36 + jj;
            int ci = (col * 57) >> 9;     // /9
            int kk = col - ci * 9;
            int ky = kk / 3, kx = kk - ky * 3;
            alds[aoff192(apx, col)] =
                f2bf(xlds[ci * 100 + (py + ky) * 10 + (pxx + kx)]);
        }
        __syncthreads();
        int arow = w * 16 + lm;
        const unsigned short* bbase = w0b + (size_t)cig * 64 * 160;
        #pragma unroll
        for (int ks = 0; ks < 5; ++ks) {
            bf16x8 a = *(const bf16x8*)&alds[aoff192(arow, ks * 32 + lq * 8)];
            #pragma unroll
            for (int n = 0; n < 4; ++n) {
                bf16x8 bb = *(const bf16x8*)(bbase + (size_t)(n * 16 + lm) * 160
                                             + ks * 32 + lq * 8);
                acc[n] = __builtin_amdgcn_mfma_f32_16x16x32_bf16(a, bb, acc[n], 0, 0, 0);
            }
        }
    }

    __syncthreads();
    float* dlds = (float*)alds;   // 64*65 floats
    #pragma unroll
    for (int n = 0; n < 4; ++n) {
        int oc = n * 16 + lm;
        #pragma unroll
        for (int r = 0; r < 4; ++r) {
            int px = w * 16 + lq * 4 + r;
            dlds[oc * 65 + px] = acc[n][r];
        }
    }
    __syncthreads();
    {
        int oc = tid >> 2;
        int ppy = tid & 3;
        float bo = b0[oc];
        float4 o4;
        #pragma unroll
        for (int ppx = 0; ppx < 4; ++ppx) {
            const float* dp = &dlds[oc * 65 + (2 * ppy) * 8 + 2 * ppx];
            float m = fmaxf(fmaxf(dp[0], dp[1]), fmaxf(dp[8], dp[9])) + bo;
            ((float*)&o4)[ppx] = m;
        }
        *(float4*)(p1 + (((size_t)b * 64 + oc) * 64 + ty * 4 + ppy) * 64 + tx * 4) = o4;
    }
}

// ---------------- K2: FUSED 1x1 (64->32) + 3x3 pad=1 (32->32) -> t3
// grid 256 = b(4) * ty(8) * tx(8); block 256 = 4 waves. (round-7 proven)
__global__ __launch_bounds__(256) void k_conv13(const float* __restrict__ p1,
                                                const unsigned short* __restrict__ w1b,
                                                const float* __restrict__ b1,
                                                const unsigned short* __restrict__ w2b,
                                                const float* __restrict__ b2,
                                                float* __restrict__ t3) {
    int blk = blockIdx.x;
    int tx = blk & 7;
    int ty = (blk >> 3) & 7;
    int b = blk >> 6;
    int tid = threadIdx.x;
    int w = tid >> 6;
    int lane = tid & 63;
    int lm = lane & 15;
    int lq = lane >> 4;
    int oy0 = ty * 8, ox0 = tx * 8;

    __shared__ __align__(16) float t2b[32 * 100];            // 12800 B
    __shared__ __align__(16) unsigned short areg[64 * 192];  // 24576 B (A1/A3/dlds)

    // ---- step 1: stage p1 halo -> A1 bf16 [px100][ci64] (zero-padded)
    const float* pb = p1 + (size_t)(b * 64) * 4096;
    #pragma unroll
    for (int j = 0; j < 25; ++j) {
        int i = tid + j * 256;        // 0..6399
        int ci = i / 100;
        int pp = i - ci * 100;
        int rr = pp / 10, cc = pp - rr * 10;
        int gy = oy0 + rr - 1, gx = ox0 + cc - 1;
        bool ok = (gy >= 0) & (gy < 64) & (gx >= 0) & (gx < 64);
        float v = ok ? pb[(size_t)ci * 4096 + gy * 64 + gx] : 0.f;
        areg[aoff80(pp, ci)] = f2bf(v);
    }
    __syncthreads();

    // ---- step 2: 1x1 MFMA. 7 row-tiles over 4 waves (w, w+4).
    #pragma unroll
    for (int s7 = 0; s7 < 2; ++s7) {
        int rt = w + s7 * 4;
        if (rt < 7) {
            f32x4 a1[2];
            a1[0] = (f32x4){0.f, 0.f, 0.f, 0.f};
            a1[1] = (f32x4){0.f, 0.f, 0.f, 0.f};
            #pragma unroll
            for (int ks = 0; ks < 2; ++ks) {
                bf16x8 a = *(const bf16x8*)&areg[aoff80(rt * 16 + lm, ks * 32 + lq * 8)];
                #pragma unroll
                for (int n = 0; n < 2; ++n) {
                    bf16x8 bb = *(const bf16x8*)(w1b + (size_t)(n * 16 + lm) * 64
                                                 + ks * 32 + lq * 8);
                    a1[n] = __builtin_amdgcn_mfma_f32_16x16x32_bf16(a, bb, a1[n], 0, 0, 0);
                }
            }
            #pragma unroll
            for (int n = 0; n < 2; ++n) {
                int oc = n * 16 + lm;
                float bv = b1[oc];
                #pragma unroll
                for (int r = 0; r < 4; ++r) {
                    int px = rt * 16 + lq * 4 + r;
                    if (px < 100) t2b[oc * 100 + px] = a1[n][r] + bv;
                }
            }
        }
    }
    __syncthreads();              // t2b complete; A1 dead

    // ---- steps 3/4: conv3 via 2 cig rounds on A3 [64px][144+16pad]
    int apx = tid >> 2, acq = tid & 3;
    int py = apx >> 3, pxx = apx & 7;
    f32x4 acc3[2];
    acc3[0] = (f32x4){0.f, 0.f, 0.f, 0.f};
    acc3[1] = (f32x4){0.f, 0.f, 0.f, 0.f};
    if (tid < 128) {              // zero pad cols 144..159 (after A1 reads done)
        *(bf16x8*)&areg[aoff192(tid >> 1, 144 + (tid & 1) * 8)] =
            (bf16x8){0, 0, 0, 0, 0, 0, 0, 0};
    }
    #pragma unroll 1
    for (int cig = 0; cig < 2; ++cig) {
        __syncthreads();          // pad visible (cig0) / prev MFMA reads done
        #pragma unroll
        for (int jj = 0; jj < 36; ++jj) {
            int col = acq * 36 + jj;
            int ci = (col * 57) >> 9;
            int kk = col - ci * 9;
            int ky = kk / 3, kx = kk - ky * 3;
            areg[aoff192(apx, col)] =
                f2bf(t2b[(cig * 16 + ci) * 100 + (py + ky) * 10 + (pxx + kx)]);
        }
        __syncthreads();
        int arow = w * 16 + lm;
        const unsigned short* bbase = w2b + (size_t)cig * 32 * 160;
        #pragma unroll
        for (int ks = 0; ks < 5; ++ks) {
            bf16x8 a = *(const bf16x8*)&areg[aoff192(arow, ks * 32 + lq * 8)];
            #pragma unroll
            for (int n = 0; n < 2; ++n) {
                bf16x8 bb = *(const bf16x8*)(bbase + (size_t)(n * 16 + lm) * 160
                                             + ks * 32 + lq * 8);
                acc3[n] = __builtin_amdgcn_mfma_f32_16x16x32_bf16(a, bb, acc3[n], 0, 0, 0);
            }
        }
    }

    // ---- epilogue: D[64px][32oc] -> LDS -> bias -> t3
    __syncthreads();
    float* dlds = (float*)areg;   // 32*65 floats = 8320 B
    #pragma unroll
    for (int n = 0; n < 2; ++n) {
        int oc = n * 16 + lm;
        #pragma unroll
        for (int r = 0; r < 4; ++r) {
            int px = w * 16 + lq * 4 + r;
            dlds[oc * 65 + px] = acc3[n][r];
        }
    }
    __syncthreads();
    {
        int oc = tid >> 3;        // 0..31
        int r = tid & 7;
        float bo = b2[oc];
        const float* dp = &dlds[oc * 65 + r * 8];
        float* op = t3 + ((size_t)(b * 32 + oc) * 64 + oy0 + r) * 64 + ox0;
        float4 a4 = make_float4(dp[0] + bo, dp[1] + bo, dp[2] + bo, dp[3] + bo);
        float4 b4 = make_float4(dp[4] + bo, dp[5] + bo, dp[6] + bo, dp[7] + bo);
        *(float4*)(op) = a4;
        *(float4*)(op + 4) = b4;
    }
}

// ---------------- K5: deformable conv (v5 body, proven 84us) + XCD swizzle
// grid 1024. Bijective remap: XCD k=blk&7 hosts batch b=k&3 only (L2
// locality heuristic, measured-neutral but free). s_setprio(1) wraps
// phase-2 MFMA. Per sub-phase s: 18 f16-MFMA offset tiles -> soff; 2304
// gather tasks -> bf16 A-tile; per half: 9x4 bf16-MFMA D[64px][64oc].
__global__ __launch_bounds__(256, 3) void k_deform(const float* __restrict__ x,
                                                   const float* __restrict__ t3,
                                                   const __half* __restrict__ w3h,
                                                   const float* __restrict__ b3,
                                                   const unsigned short* __restrict__ wdtb,
                                                   float* __restrict__ out) {
    int blk = blockIdx.x;
    int k8 = blk & 7;             // XCD (dispatch round-robin heuristic)
    int j8 = blk >> 3;            // 0..127
    int b = k8 & 3;               // batch clustered per XCD
    int strip = j8 * 2 + (k8 >> 2);   // 0..255, bijective
    int tid = threadIdx.x;
    int po0 = strip * 16;
    int qy = po0 >> 6;            // strip lies in one quad-row
    int qx0 = po0 & 63;
    int w = tid >> 6;             // wave id
    int lane = tid & 63;
    int lm = lane & 15;
    int lq = lane >> 4;
    int tq = tid & 15;            // pooled-px column this thread serves (fixed)
    int kb = tid >> 4;            // kcol = it*16 + kb

    __shared__ __align__(16) unsigned short alds[64 * 320];   // 40960 B
    __shared__ __align__(16) __half2 soff[2304];              //  9216 B
    __shared__ __align__(16) _Float16 st3t[16 * 40];          //  1280 B

    f32x4 acc[4];
    #pragma unroll
    for (int n = 0; n < 4; ++n) acc[n] = (f32x4){0.f, 0.f, 0.f, 0.f};

    const float* xb = x + (size_t)b * 64 * HX * WX;
    float fybase = (float)(2 * qy);
    float fxbase = (float)(2 * (qx0 + tq));

    // ---- stage t3 tile (32 ci x 16 px) to LDS as fp16, px-major pitch 40
    {
        int px = tid & 15, ci0 = tid >> 4;    // ci0 0..15
        const float* t3p = t3 + (size_t)b * 32 * 4096 + (qy * 64 + qx0 + px);
        st3t[px * 40 + ci0]      = (_Float16)t3p[(size_t)ci0 * 4096];
        st3t[px * 40 + ci0 + 16] = (_Float16)t3p[(size_t)(ci0 + 16) * 4096];
    }
    __syncthreads();
    // B-frag (t3) for the offset MFMA: lane holds t3[px=lm][ci=lq*8+j].
    const f16x8 bfrag = *(const f16x8*)&st3t[lm * 40 + lq * 8];

    for (int h = 0; h < 2; ++h) {
        #pragma unroll 1
        for (int sl = 0; sl < 2; ++sl) {
            int s = h * 2 + sl;           // sup = 16 channels
            __syncthreads();              // alds+soff free (prev phase done)

            // ---- phase 1a: offsets via f16 MFMA. 18 tiles of 16 off-ch.
            #pragma unroll
            for (int rep = 0; rep < 5; ++rep) {
                int t = rep * 4 + w;
                if (rep == 4) { if (w >= 2) break; t = 16 + w; }
                const f16x8 afrag = *(const f16x8*)((const _Float16*)w3h
                        + (size_t)(s * 288 + t * 16 + lm) * 32 + lq * 8);
                f32x4 d = __builtin_amdgcn_mfma_f32_16x16x32_f16(
                        afrag, bfrag, (f32x4){0.f, 0.f, 0.f, 0.f}, 0, 0, 0);
                float4 bq = *(const float4*)(b3 + s * 288 + t * 16 + lq * 4);
                int p0 = (t * 8 + lq * 2) * 16 + lm;   // pair-slot kcol*16+px
                soff[p0]      = __floats2half2_rn(d[0] + bq.x, d[1] + bq.y);
                soff[p0 + 16] = __floats2half2_rn(d[2] + bq.z, d[3] + bq.w);
            }
            __syncthreads();              // soff visible

            // ---- phase 1b: prefetch 9 offset pairs (word = it*256 + tid)
            __half2 o2h[9];
            #pragma unroll
            for (int it = 0; it < 9; ++it)
                o2h[it] = soff[it * 256 + tid];
            // bilinear gather -> 4 bf16 A-tile rows per task
            #pragma unroll
            for (int it = 0; it < 9; ++it) {
                int kcol = it * 16 + kb;      // 0..143
                int lc = kcol >= 72;
                int ckk = kcol - 72 * lc;     // 0..71
                int ch = (ckk * 57) >> 9;     // /9
                int kk = ckk - ch * 9;
                int c = s * 16 + lc * 8 + ch;
                int clocal = sl * 144 + kcol; // A column 0..287
                float2 off = __half22float2(o2h[it]);
                float py = off.x + fybase + (float)(kk / 3);
                float px = off.y + fxbase + (float)(kk % 3);
                float y0f = floorf(py), x0f = floorf(px);
                float fy = py - y0f, fx = px - x0f;
                int y0 = (int)y0f, x0 = (int)x0f;
                const float* xp = xb + (size_t)c * (HX * WX);
                float tv[3][3];
                bool fastok = (y0 >= 0) & (y0 <= HX - 3) & (x0 >= 0) & (x0 <= WX - 3);
                if (__all(fastok)) {
                    // whole wave in-bounds: even-aligned float2 pair per row
                    int xe = x0 & ~1;         // even -> 8B-aligned (WX even)
                    int odd = x0 & 1;
                    const float* rp = xp + y0 * WX + xe;
                    #pragma unroll
                    for (int r = 0; r < 3; ++r) {
                        float2 A = *(const float2*)(rp);
                        float2 B = *(const float2*)(rp + 2);
                        tv[r][0] = odd ? A.y : A.x;
                        tv[r][1] = odd ? B.x : A.y;
                        tv[r][2] = odd ? B.y : B.x;
                        rp += WX;
                    }
                } else {
                    #pragma unroll
                    for (int r = 0; r < 3; ++r) {
                        int yy = y0 + r;
                        bool vy = (yy >= 0) & (yy < HX);
                        int yc = min(max(yy, 0), HX - 1);
                        #pragma unroll
                        for (int sx = 0; sx < 3; ++sx) {
                            int xx = x0 + sx;
                            bool vx = (xx >= 0) & (xx < WX);
                            int xc = min(max(xx, 0), WX - 1);
                            float val = xp[yc * WX + xc];
                            tv[r][sx] = (vy & vx) ? val : 0.f;
                        }
                    }
                }
                float h0[3], h1[3];
                #pragma unroll
                for (int r = 0; r < 3; ++r) {
                    h0[r] = tv[r][0] + fx * (tv[r][1] - tv[r][0]);
                    h1[r] = tv[r][1] + fx * (tv[r][2] - tv[r][1]);
                }
                alds[aoff320(0 * 16 + tq, clocal)] = f2bf(h0[0] + fy * (h0[1] - h0[0]));
                alds[aoff320(1 * 16 + tq, clocal)] = f2bf(h1[0] + fy * (h1[1] - h1[0]));
                alds[aoff320(2 * 16 + tq, clocal)] = f2bf(h0[1] + fy * (h0[2] - h0[1]));
                alds[aoff320(3 * 16 + tq, clocal)] = f2bf(h1[1] + fy * (h1[2] - h1[1]));
            }
        }
        __syncthreads();          // A-tile (288 cols) visible

        // ---- phase 2: D[64px][64oc] += V[64][288] . W^T  (MFMA bf16)
        int arow = w * 16 + lm;
        const unsigned short* bbase = wdtb + (size_t)(h * 64) * 288;
        __builtin_amdgcn_s_setprio(1);
        #pragma unroll
        for (int ks = 0; ks < 9; ++ks) {
            bf16x8 a = *(const bf16x8*)&alds[aoff320(arow, ks * 32 + lq * 8)];
            #pragma unroll
            for (int n = 0; n < 4; ++n) {
                bf16x8 bb = *(const bf16x8*)(bbase + (size_t)(n * 16 + lm) * 288
                                             + ks * 32 + lq * 8);
                acc[n] = __builtin_amdgcn_mfma_f32_16x16x32_bf16(a, bb, acc[n], 0, 0, 0);
            }
        }
        __builtin_amdgcn_s_setprio(0);
    }

    // ---- epilogue via LDS: D lane layout -> [oc][px] -> coalesced stores
    __syncthreads();              // all phase-2 reads of alds complete
    float* dlds = (float*)alds;   // 64*65 = 4160 floats
    #pragma unroll
    for (int n = 0; n < 4; ++n) {
        int oc = n * 16 + lm;
        #pragma unroll
        for (int r = 0; r < 4; ++r) {
            int px = w * 16 + lq * 4 + r;     // = sub*16 + q
            dlds[oc * 65 + px] = acc[n][r];
        }
    }
    __syncthreads();
    {
        int oc = tid >> 2;
        int sy = (tid >> 1) & 1;
        int qh = (tid & 1) * 8;
        float* orow = out + (((size_t)b * 64 + oc) * 128 + 2 * qy + sy) * 128 + 2 * qx0;
        const float* d0 = &dlds[oc * 65 + (sy * 2 + 0) * 16];
        const float* d1 = &dlds[oc * 65 + (sy * 2 + 1) * 16];
        #pragma unroll
        for (int i = 0; i < 8; ++i) {
            int q = qh + i;
            *(float2*)(orow + 2 * q) = make_float2(d0[q], d1[q]);
        }
    }
}

extern "C" void kernel_launch(void* const* d_in, const int* in_sizes, int n_in,
                              void* d_out, int out_size, void* d_ws, size_t ws_size,
                              hipStream_t stream) {
    const float* x  = (const float*)d_in[0];
    const float* w0 = (const float*)d_in[1];
    const float* b0 = (const float*)d_in[2];
    const float* w1 = (const float*)d_in[3];
    const float* b1 = (const float*)d_in[4];
    const float* w2 = (const float*)d_in[5];
    const float* b2 = (const float*)d_in[6];
    const float* w3 = (const float*)d_in[7];
    const float* b3 = (const float*)d_in[8];
    const float* wd = (const float*)d_in[9];
    float* out = (float*)d_out;

    float* ws = (float*)d_ws;
    float* p1    = ws;                       // 1,048,576 floats
    float* t3    = p1 + 1048576;             //   524,288
    unsigned short* wdtb = (unsigned short*)(t3 + 524288);  // 36,864 + 16 pad
    __half* w3h = (__half*)(wdtb + 36880);   // 36,864 fp16 (16B-aligned)
    unsigned short* w0b = (unsigned short*)(w3h + 36864);   // 40,960 bf16
    unsigned short* w2b = w0b + 40960;                      // 10,240 bf16
    unsigned short* w1b = w2b + 10240;                      //  2,048 bf16

    k_wdt<<<496, 256, 0, stream>>>(wd, w3, w0, w2, w1, wdtb, w3h, w0b, w2b, w1b);
    k_conv0_mfma<<<1024, 256, 0, stream>>>(x, w0b, b0, p1);
    k_conv13<<<256, 256, 0, stream>>>(p1, w1b, b1, w2b, b2, t3);
    k_deform<<<1024, 256, 0, stream>>>(x, t3, w3h, b3, wdtb, out);
}

// Round 13
// 215.852 us; speedup vs baseline: 1.1006x; 1.0336x over previous
//
#include <hip/hip_runtime.h>
#include <hip/hip_bf16.h>
#include <hip/hip_fp16.h>

// Pipeline:
//  x (4,64,130,130) --conv3x3 valid + bias + maxpool2x2 (MFMA)--> p1 (4,64,64,64)
//  p1 --[FUSED k_conv13: 1x1 (64->32) MFMA in LDS + 3x3 pad=1 MFMA]--> t3
//  [FUSED] offset conv (32->1152) computed INSIDE k_deform via f16 MFMA
//  deform_conv(x, upsample2x(offsets), wd) -> out (4,64,128,128)
//
//  Round-13 change: k_conv13 widened to 512 threads (8 waves), grid 256.
//   - conv13 was the chain's weakest occupancy point: 1 block/CU x 4 waves
//     = 1 wave/SIMD on a serial stage->MFMA->build->MFMA chain. 8 waves =
//     2/SIMD halves per-thread issue counts (stage 25->13 iters, A3 build
//     36->18 cols) and overlaps load latency. conv3 MFMA splits N=32 over
//     wave-groups (w>>2 = n). Dataflow/LDS/swizzles unchanged, only
//     tid->task maps rescaled.
//   - k_deform = v5 body + XCD swizzle + setprio (locked, 84us floor over
//     a 7-variant ledger); conv0_mfma, k_wdt unchanged (round-8 proven).

#define HX 130
#define WX 130

typedef short bf16x8 __attribute__((ext_vector_type(8)));
typedef _Float16 f16x8 __attribute__((ext_vector_type(8)));
typedef float f32x4 __attribute__((ext_vector_type(4)));

static __device__ __forceinline__ unsigned short f2bf(float f) {
    unsigned u = __float_as_uint(f);
    unsigned r = u + 0x7fff + ((u >> 16) & 1);   // round-to-nearest-even
    return (unsigned short)(r >> 16);
}

// A-tile address (in shorts): row pitch 320, 16B-block swizzle (k_deform v5)
static __device__ __forceinline__ int aoff320(int row, int col) {
    return row * 320 + ((((col >> 3) ^ (row & 7))) << 3) + (col & 7);
}

// A-tile address (in shorts): row pitch 192 (160-col tiles), 16B-block swizzle
static __device__ __forceinline__ int aoff192(int row, int col) {
    return row * 192 + ((((col >> 3) ^ (row & 7))) << 3) + (col & 7);
}

// A-tile address (in shorts): row pitch 80 (64-col 1x1 tile), same family
static __device__ __forceinline__ int aoff80(int row, int col) {
    return row * 80 + ((((col >> 3) ^ (row & 7))) << 3) + (col & 7);
}

// ---------------- K0: weight prep
//  idx <  36864 : wd -> bf16 wdtb[h(2)][oc(64)][col(288)]  (+16 zero tail)
//  idx <  73728 : w3 -> fp16 w3h[1152][32]
//  idx < 114688 : w0 -> bf16 w0b[cig(4)][oc(64)][160]; col=ci_l*9+kk, pad 0
//  idx < 124928 : w2 -> bf16 w2b[cig(2)][oc(32)][160]; col=ci_l*9+kk, pad 0
//  idx < 126976 : w1 -> bf16 w1b[oc(32)][64] (contiguous copy-convert)
__global__ __launch_bounds__(256) void k_wdt(const float* __restrict__ wd,
                                             const float* __restrict__ w3,
                                             const float* __restrict__ w0,
                                             const float* __restrict__ w2,
                                             const float* __restrict__ w1,
                                             unsigned short* __restrict__ wdtb,
                                             __half* __restrict__ w3h,
                                             unsigned short* __restrict__ w0b,
                                             unsigned short* __restrict__ w2b,
                                             unsigned short* __restrict__ w1b) {
    int idx = blockIdx.x * 256 + threadIdx.x;   // grid 496*256 = 126976
    if (idx < 36864) {
        int o = idx / 576;
        int rem = idx - o * 576;
        int c = rem / 9;
        int kk = rem - c * 9;
        int h = c >> 5;
        int c5 = c & 31;
        int col = (c5 >> 4) * 144 + ((c5 >> 3) & 1) * 72 + (c5 & 7) * 9 + kk;
        wdtb[(size_t)(h * 64 + o) * 288 + col] = f2bf(wd[idx]);
        if (idx < 16) wdtb[36864 + idx] = 0;    // tail pad: guard 0*NaN
    } else if (idx < 73728) {
        int i2 = idx - 36864;
        w3h[i2] = __float2half_rn(w3[i2]);
    } else if (idx < 114688) {
        int i3 = idx - 73728;                   // 0..40959
        int row = i3 / 160;                     // cig*64 + oc
        int col = i3 - row * 160;
        int cig = row >> 6, oc = row & 63;
        unsigned short v = 0;
        if (col < 144) {
            int ci = (col * 57) >> 9;           // /9, valid col<144
            int kk = col - ci * 9;
            v = f2bf(w0[(size_t)(oc * 64 + cig * 16 + ci) * 9 + kk]);
        }
        w0b[i3] = v;
    } else if (idx < 124928) {
        int i4 = idx - 114688;                  // 0..10239
        int row = i4 / 160;                     // cig*32 + oc
        int col = i4 - row * 160;
        int cig = row >> 5, oc = row & 31;
        unsigned short v = 0;
        if (col < 144) {
            int ci = (col * 57) >> 9;
            int kk = col - ci * 9;
            v = f2bf(w2[(size_t)(oc * 32 + cig * 16 + ci) * 9 + kk]);
        }
        w2b[i4] = v;
    } else {
        int i5 = idx - 124928;                  // 0..2047
        w1b[i5] = f2bf(w1[i5]);
    }
}

// ---------------- K1: conv3x3 valid (64->64) via MFMA + bias + maxpool -> p1
// grid 1024 = b(4) * ty(16) * tx(16); block 256 = 4 waves. (round-5 proven)
__global__ __launch_bounds__(256, 4) void k_conv0_mfma(const float* __restrict__ x,
                                                       const unsigned short* __restrict__ w0b,
                                                       const float* __restrict__ b0,
                                                       float* __restrict__ p1) {
    int blk = blockIdx.x;
    int tx = blk & 15;
    int ty = (blk >> 4) & 15;
    int b = blk >> 8;
    int tid = threadIdx.x;
    int w = tid >> 6;
    int lane = tid & 63;
    int lm = lane & 15;
    int lq = lane >> 4;
    int oy0 = ty * 8, ox0 = tx * 8;

    __shared__ __align__(16) unsigned short alds[64 * 192];   // 24576 B
    __shared__ __align__(16) float xlds[1600];                //  6400 B

    f32x4 acc[4];
    #pragma unroll
    for (int n = 0; n < 4; ++n) acc[n] = (f32x4){0.f, 0.f, 0.f, 0.f};

    if (tid < 128) {
        *(bf16x8*)&alds[aoff192(tid >> 1, 144 + (tid & 1) * 8)] =
            (bf16x8){0, 0, 0, 0, 0, 0, 0, 0};
    }

    const float* xb = x + (size_t)(b * 64) * (HX * WX) + oy0 * WX + ox0;
    int apx = tid >> 2;           // 0..63 conv px (py*8+pxx)
    int acq = tid & 3;            // col slice
    int py = apx >> 3, pxx = apx & 7;

    for (int cig = 0; cig < 4; ++cig) {
        #pragma unroll
        for (int j = 0; j < 7; ++j) {
            int i = tid + j * 256;
            if (i < 1600) {
                int ci = i / 100;
                int rem = i - ci * 100;
                int rr = rem / 10, cc = rem - rr * 10;
                xlds[i] = xb[(size_t)(cig * 16 + ci) * (HX * WX) + rr * WX + cc];
            }
        }
        __syncthreads();
        #pragma unroll
        for (int jj = 0; jj < 36; ++jj) {
            int col = acq * 36 + jj;
            int ci = (col * 57) >> 9;     // /9
            int kk = col - ci * 9;
            int ky = kk / 3, kx = kk - ky * 3;
            alds[aoff192(apx, col)] =
                f2bf(xlds[ci * 100 + (py + ky) * 10 + (pxx + kx)]);
        }
        __syncthreads();
        int arow = w * 16 + lm;
        const unsigned short* bbase = w0b + (size_t)cig * 64 * 160;
        #pragma unroll
        for (int ks = 0; ks < 5; ++ks) {
            bf16x8 a = *(const bf16x8*)&alds[aoff192(arow, ks * 32 + lq * 8)];
            #pragma unroll
            for (int n = 0; n < 4; ++n) {
                bf16x8 bb = *(const bf16x8*)(bbase + (size_t)(n * 16 + lm) * 160
                                             + ks * 32 + lq * 8);
                acc[n] = __builtin_amdgcn_mfma_f32_16x16x32_bf16(a, bb, acc[n], 0, 0, 0);
            }
        }
    }

    __syncthreads();
    float* dlds = (float*)alds;   // 64*65 floats
    #pragma unroll
    for (int n = 0; n < 4; ++n) {
        int oc = n * 16 + lm;
        #pragma unroll
        for (int r = 0; r < 4; ++r) {
            int px = w * 16 + lq * 4 + r;
            dlds[oc * 65 + px] = acc[n][r];
        }
    }
    __syncthreads();
    {
        int oc = tid >> 2;
        int ppy = tid & 3;
        float bo = b0[oc];
        float4 o4;
        #pragma unroll
        for (int ppx = 0; ppx < 4; ++ppx) {
            const float* dp = &dlds[oc * 65 + (2 * ppy) * 8 + 2 * ppx];
            float m = fmaxf(fmaxf(dp[0], dp[1]), fmaxf(dp[8], dp[9])) + bo;
            ((float*)&o4)[ppx] = m;
        }
        *(float4*)(p1 + (((size_t)b * 64 + oc) * 64 + ty * 4 + ppy) * 64 + tx * 4) = o4;
    }
}

// ---------------- K2: FUSED 1x1 (64->32) + 3x3 pad=1 (32->32) -> t3
// grid 256 = b(4) * ty(8) * tx(8); block 512 = 8 waves (2 waves/SIMD).
// Same dataflow as the round-7 256-thread version; tid->task maps rescaled.
__global__ __launch_bounds__(512) void k_conv13(const float* __restrict__ p1,
                                                const unsigned short* __restrict__ w1b,
                                                const float* __restrict__ b1,
                                                const unsigned short* __restrict__ w2b,
                                                const float* __restrict__ b2,
                                                float* __restrict__ t3) {
    int blk = blockIdx.x;
    int tx = blk & 7;
    int ty = (blk >> 3) & 7;
    int b = blk >> 6;
    int tid = threadIdx.x;
    int w = tid >> 6;             // 0..7
    int lane = tid & 63;
    int lm = lane & 15;
    int lq = lane >> 4;
    int oy0 = ty * 8, ox0 = tx * 8;

    __shared__ __align__(16) float t2b[32 * 100];            // 12800 B
    __shared__ __align__(16) unsigned short areg[64 * 192];  // 24576 B (A1/A3/dlds)

    // ---- step 1: stage p1 halo -> A1 bf16 [px100][ci64] (zero-padded)
    const float* pb = p1 + (size_t)(b * 64) * 4096;
    #pragma unroll
    for (int j = 0; j < 13; ++j) {
        int i = tid + j * 512;        // 0..6399
        if (i < 6400) {
            int ci = i / 100;
            int pp = i - ci * 100;
            int rr = pp / 10, cc = pp - rr * 10;
            int gy = oy0 + rr - 1, gx = ox0 + cc - 1;
            bool ok = (gy >= 0) & (gy < 64) & (gx >= 0) & (gx < 64);
            float v = ok ? pb[(size_t)ci * 4096 + gy * 64 + gx] : 0.f;
            areg[aoff80(pp, ci)] = f2bf(v);
        }
    }
    __syncthreads();

    // ---- step 2: 1x1 MFMA. 7 row-tiles over waves 0..6 (wave 7 idle).
    if (w < 7) {
        int rt = w;
        f32x4 a1[2];
        a1[0] = (f32x4){0.f, 0.f, 0.f, 0.f};
        a1[1] = (f32x4){0.f, 0.f, 0.f, 0.f};
        #pragma unroll
        for (int ks = 0; ks < 2; ++ks) {
            bf16x8 a = *(const bf16x8*)&areg[aoff80(rt * 16 + lm, ks * 32 + lq * 8)];
            #pragma unroll
            for (int n = 0; n < 2; ++n) {
                bf16x8 bb = *(const bf16x8*)(w1b + (size_t)(n * 16 + lm) * 64
                                             + ks * 32 + lq * 8);
                a1[n] = __builtin_amdgcn_mfma_f32_16x16x32_bf16(a, bb, a1[n], 0, 0, 0);
            }
        }
        #pragma unroll
        for (int n = 0; n < 2; ++n) {
            int oc = n * 16 + lm;
            float bv = b1[oc];
            #pragma unroll
            for (int r = 0; r < 4; ++r) {
                int px = rt * 16 + lq * 4 + r;
                if (px < 100) t2b[oc * 100 + px] = a1[n][r] + bv;
            }
        }
    }
    __syncthreads();              // t2b complete; A1 dead

    // ---- steps 3/4: conv3 via 2 cig rounds on A3 [64px][144+16pad]
    // A3 build: 8 col-slices of 18 cols (512 threads); MFMA: waves 0-3 do
    // n=0, waves 4-7 do n=1 (same A rows, different W rows).
    int apx = tid >> 3, acq = tid & 7;
    int py = apx >> 3, pxx = apx & 7;
    int wl = w & 3;               // A row-tile within group
    int ng = w >> 2;              // N half (0/1)
    f32x4 acc3 = (f32x4){0.f, 0.f, 0.f, 0.f};
    if (tid < 128) {              // zero pad cols 144..159 (after A1 reads done)
        *(bf16x8*)&areg[aoff192(tid >> 1, 144 + (tid & 1) * 8)] =
            (bf16x8){0, 0, 0, 0, 0, 0, 0, 0};
    }
    #pragma unroll 1
    for (int cig = 0; cig < 2; ++cig) {
        __syncthreads();          // pad visible (cig0) / prev MFMA reads done
        #pragma unroll
        for (int jj = 0; jj < 18; ++jj) {
            int col = acq * 18 + jj;
            int ci = (col * 57) >> 9;
            int kk = col - ci * 9;
            int ky = kk / 3, kx = kk - ky * 3;
            areg[aoff192(apx, col)] =
                f2bf(t2b[(cig * 16 + ci) * 100 + (py + ky) * 10 + (pxx + kx)]);
        }
        __syncthreads();
        int arow = wl * 16 + lm;
        const unsigned short* bbase = w2b + (size_t)cig * 32 * 160;
        #pragma unroll
        for (int ks = 0; ks < 5; ++ks) {
            bf16x8 a = *(const bf16x8*)&areg[aoff192(arow, ks * 32 + lq * 8)];
            bf16x8 bb = *(const bf16x8*)(bbase + (size_t)(ng * 16 + lm) * 160
                                         + ks * 32 + lq * 8);
            acc3 = __builtin_amdgcn_mfma_f32_16x16x32_bf16(a, bb, acc3, 0, 0, 0);
        }
    }

    // ---- epilogue: D[64px][32oc] -> LDS -> bias -> t3
    __syncthreads();
    float* dlds = (float*)areg;   // 32*65 floats = 8320 B
    {
        int oc = ng * 16 + lm;
        #pragma unroll
        for (int r = 0; r < 4; ++r) {
            int px = wl * 16 + lq * 4 + r;
            dlds[oc * 65 + px] = acc3[r];
        }
    }
    __syncthreads();
    {
        int oc = tid >> 4;        // 0..31
        int rem = tid & 15;
        int r = rem >> 1;         // out row within region
        int xh = rem & 1;         // half-row (4 px)
        float bo = b2[oc];
        const float* dp = &dlds[oc * 65 + r * 8 + xh * 4];
        float* op = t3 + ((size_t)(b * 32 + oc) * 64 + oy0 + r) * 64 + ox0 + xh * 4;
        *(float4*)(op) = make_float4(dp[0] + bo, dp[1] + bo, dp[2] + bo, dp[3] + bo);
    }
}

// ---------------- K5: deformable conv (v5 body, proven 84us) + XCD swizzle
// grid 1024. Bijective remap: XCD k=blk&7 hosts batch b=k&3 only (L2
// locality heuristic, measured-neutral but free). s_setprio(1) wraps
// phase-2 MFMA. Per sub-phase s: 18 f16-MFMA offset tiles -> soff; 2304
// gather tasks -> bf16 A-tile; per half: 9x4 bf16-MFMA D[64px][64oc].
__global__ __launch_bounds__(256, 3) void k_deform(const float* __restrict__ x,
                                                   const float* __restrict__ t3,
                                                   const __half* __restrict__ w3h,
                                                   const float* __restrict__ b3,
                                                   const unsigned short* __restrict__ wdtb,
                                                   float* __restrict__ out) {
    int blk = blockIdx.x;
    int k8 = blk & 7;             // XCD (dispatch round-robin heuristic)
    int j8 = blk >> 3;            // 0..127
    int b = k8 & 3;               // batch clustered per XCD
    int strip = j8 * 2 + (k8 >> 2);   // 0..255, bijective
    int tid = threadIdx.x;
    int po0 = strip * 16;
    int qy = po0 >> 6;            // strip lies in one quad-row
    int qx0 = po0 & 63;
    int w = tid >> 6;             // wave id
    int lane = tid & 63;
    int lm = lane & 15;
    int lq = lane >> 4;
    int tq = tid & 15;            // pooled-px column this thread serves (fixed)
    int kb = tid >> 4;            // kcol = it*16 + kb

    __shared__ __align__(16) unsigned short alds[64 * 320];   // 40960 B
    __shared__ __align__(16) __half2 soff[2304];              //  9216 B
    __shared__ __align__(16) _Float16 st3t[16 * 40];          //  1280 B

    f32x4 acc[4];
    #pragma unroll
    for (int n = 0; n < 4; ++n) acc[n] = (f32x4){0.f, 0.f, 0.f, 0.f};

    const float* xb = x + (size_t)b * 64 * HX * WX;
    float fybase = (float)(2 * qy);
    float fxbase = (float)(2 * (qx0 + tq));

    // ---- stage t3 tile (32 ci x 16 px) to LDS as fp16, px-major pitch 40
    {
        int px = tid & 15, ci0 = tid >> 4;    // ci0 0..15
        const float* t3p = t3 + (size_t)b * 32 * 4096 + (qy * 64 + qx0 + px);
        st3t[px * 40 + ci0]      = (_Float16)t3p[(size_t)ci0 * 4096];
        st3t[px * 40 + ci0 + 16] = (_Float16)t3p[(size_t)(ci0 + 16) * 4096];
    }
    __syncthreads();
    // B-frag (t3) for the offset MFMA: lane holds t3[px=lm][ci=lq*8+j].
    const f16x8 bfrag = *(const f16x8*)&st3t[lm * 40 + lq * 8];

    for (int h = 0; h < 2; ++h) {
        #pragma unroll 1
        for (int sl = 0; sl < 2; ++sl) {
            int s = h * 2 + sl;           // sup = 16 channels
            __syncthreads();              // alds+soff free (prev phase done)

            // ---- phase 1a: offsets via f16 MFMA. 18 tiles of 16 off-ch.
            #pragma unroll
            for (int rep = 0; rep < 5; ++rep) {
                int t = rep * 4 + w;
                if (rep == 4) { if (w >= 2) break; t = 16 + w; }
                const f16x8 afrag = *(const f16x8*)((const _Float16*)w3h
                        + (size_t)(s * 288 + t * 16 + lm) * 32 + lq * 8);
                f32x4 d = __builtin_amdgcn_mfma_f32_16x16x32_f16(
                        afrag, bfrag, (f32x4){0.f, 0.f, 0.f, 0.f}, 0, 0, 0);
                float4 bq = *(const float4*)(b3 + s * 288 + t * 16 + lq * 4);
                int p0 = (t * 8 + lq * 2) * 16 + lm;   // pair-slot kcol*16+px
                soff[p0]      = __floats2half2_rn(d[0] + bq.x, d[1] + bq.y);
                soff[p0 + 16] = __floats2half2_rn(d[2] + bq.z, d[3] + bq.w);
            }
            __syncthreads();              // soff visible

            // ---- phase 1b: prefetch 9 offset pairs (word = it*256 + tid)
            __half2 o2h[9];
            #pragma unroll
            for (int it = 0; it < 9; ++it)
                o2h[it] = soff[it * 256 + tid];
            // bilinear gather -> 4 bf16 A-tile rows per task
            #pragma unroll
            for (int it = 0; it < 9; ++it) {
                int kcol = it * 16 + kb;      // 0..143
                int lc = kcol >= 72;
                int ckk = kcol - 72 * lc;     // 0..71
                int ch = (ckk * 57) >> 9;     // /9
                int kk = ckk - ch * 9;
                int c = s * 16 + lc * 8 + ch;
                int clocal = sl * 144 + kcol; // A column 0..287
                float2 off = __half22float2(o2h[it]);
                float py = off.x + fybase + (float)(kk / 3);
                float px = off.y + fxbase + (float)(kk % 3);
                float y0f = floorf(py), x0f = floorf(px);
                float fy = py - y0f, fx = px - x0f;
                int y0 = (int)y0f, x0 = (int)x0f;
                const float* xp = xb + (size_t)c * (HX * WX);
                float tv[3][3];
                bool fastok = (y0 >= 0) & (y0 <= HX - 3) & (x0 >= 0) & (x0 <= WX - 3);
                if (__all(fastok)) {
                    // whole wave in-bounds: even-aligned float2 pair per row
                    int xe = x0 & ~1;         // even -> 8B-aligned (WX even)
                    int odd = x0 & 1;
                    const float* rp = xp + y0 * WX + xe;
                    #pragma unroll
                    for (int r = 0; r < 3; ++r) {
                        float2 A = *(const float2*)(rp);
                        float2 B = *(const float2*)(rp + 2);
                        tv[r][0] = odd ? A.y : A.x;
                        tv[r][1] = odd ? B.x : A.y;
                        tv[r][2] = odd ? B.y : B.x;
                        rp += WX;
                    }
                } else {
                    #pragma unroll
                    for (int r = 0; r < 3; ++r) {
                        int yy = y0 + r;
                        bool vy = (yy >= 0) & (yy < HX);
                        int yc = min(max(yy, 0), HX - 1);
                        #pragma unroll
                        for (int sx = 0; sx < 3; ++sx) {
                            int xx = x0 + sx;
                            bool vx = (xx >= 0) & (xx < WX);
                            int xc = min(max(xx, 0), WX - 1);
                            float val = xp[yc * WX + xc];
                            tv[r][sx] = (vy & vx) ? val : 0.f;
                        }
                    }
                }
                float h0[3], h1[3];
                #pragma unroll
                for (int r = 0; r < 3; ++r) {
                    h0[r] = tv[r][0] + fx * (tv[r][1] - tv[r][0]);
                    h1[r] = tv[r][1] + fx * (tv[r][2] - tv[r][1]);
                }
                alds[aoff320(0 * 16 + tq, clocal)] = f2bf(h0[0] + fy * (h0[1] - h0[0]));
                alds[aoff320(1 * 16 + tq, clocal)] = f2bf(h1[0] + fy * (h1[1] - h1[0]));
                alds[aoff320(2 * 16 + tq, clocal)] = f2bf(h0[1] + fy * (h0[2] - h0[1]));
                alds[aoff320(3 * 16 + tq, clocal)] = f2bf(h1[1] + fy * (h1[2] - h1[1]));
            }
        }
        __syncthreads();          // A-tile (288 cols) visible

        // ---- phase 2: D[64px][64oc] += V[64][288] . W^T  (MFMA bf16)
        int arow = w * 16 + lm;
        const unsigned short* bbase = wdtb + (size_t)(h * 64) * 288;
        __builtin_amdgcn_s_setprio(1);
        #pragma unroll
        for (int ks = 0; ks < 9; ++ks) {
            bf16x8 a = *(const bf16x8*)&alds[aoff320(arow, ks * 32 + lq * 8)];
            #pragma unroll
            for (int n = 0; n < 4; ++n) {
                bf16x8 bb = *(const bf16x8*)(bbase + (size_t)(n * 16 + lm) * 288
                                             + ks * 32 + lq * 8);
                acc[n] = __builtin_amdgcn_mfma_f32_16x16x32_bf16(a, bb, acc[n], 0, 0, 0);
            }
        }
        __builtin_amdgcn_s_setprio(0);
    }

    // ---- epilogue via LDS: D lane layout -> [oc][px] -> coalesced stores
    __syncthreads();              // all phase-2 reads of alds complete
    float* dlds = (float*)alds;   // 64*65 = 4160 floats
    #pragma unroll
    for (int n = 0; n < 4; ++n) {
        int oc = n * 16 + lm;
        #pragma unroll
        for (int r = 0; r < 4; ++r) {
            int px = w * 16 + lq * 4 + r;     // = sub*16 + q
            dlds[oc * 65 + px] = acc[n][r];
        }
    }
    __syncthreads();
    {
        int oc = tid >> 2;
        int sy = (tid >> 1) & 1;
        int qh = (tid & 1) * 8;
        float* orow = out + (((size_t)b * 64 + oc) * 128 + 2 * qy + sy) * 128 + 2 * qx0;
        const float* d0 = &dlds[oc * 65 + (sy * 2 + 0) * 16];
        const float* d1 = &dlds[oc * 65 + (sy * 2 + 1) * 16];
        #pragma unroll
        for (int i = 0; i < 8; ++i) {
            int q = qh + i;
            *(float2*)(orow + 2 * q) = make_float2(d0[q], d1[q]);
        }
    }
}

extern "C" void kernel_launch(void* const* d_in, const int* in_sizes, int n_in,
                              void* d_out, int out_size, void* d_ws, size_t ws_size,
                              hipStream_t stream) {
    const float* x  = (const float*)d_in[0];
    const float* w0 = (const float*)d_in[1];
    const float* b0 = (const float*)d_in[2];
    const float* w1 = (const float*)d_in[3];
    const float* b1 = (const float*)d_in[4];
    const float* w2 = (const float*)d_in[5];
    const float* b2 = (const float*)d_in[6];
    const float* w3 = (const float*)d_in[7];
    const float* b3 = (const float*)d_in[8];
    const float* wd = (const float*)d_in[9];
    float* out = (float*)d_out;

    float* ws = (float*)d_ws;
    float* p1    = ws;                       // 1,048,576 floats
    float* t3    = p1 + 1048576;             //   524,288
    unsigned short* wdtb = (unsigned short*)(t3 + 524288);  // 36,864 + 16 pad
    __half* w3h = (__half*)(wdtb + 36880);   // 36,864 fp16 (16B-aligned)
    unsigned short* w0b = (unsigned short*)(w3h + 36864);   // 40,960 bf16
    unsigned short* w2b = w0b + 40960;                      // 10,240 bf16
    unsigned short* w1b = w2b + 10240;                      //  2,048 bf16

    k_wdt<<<496, 256, 0, stream>>>(wd, w3, w0, w2, w1, wdtb, w3h, w0b, w2b, w1b);
    k_conv0_mfma<<<1024, 256, 0, stream>>>(x, w0b, b0, p1);
    k_conv13<<<256, 512, 0, stream>>>(p1, w1b, b1, w2b, b2, t3);
    k_deform<<<1024, 256, 0, stream>>>(x, t3, w3h, b3, wdtb, out);
}

// Round 14
// 211.676 us; speedup vs baseline: 1.1224x; 1.0197x over previous
//
#include <hip/hip_runtime.h>
#include <hip/hip_bf16.h>
#include <hip/hip_fp16.h>

// Pipeline:
//  x (4,64,130,130) --conv3x3 valid + bias + maxpool2x2 (MFMA)--> p1 (4,64,64,64)
//  p1 --[FUSED k_conv13: 1x1 (64->32) MFMA in LDS + 3x3 pad=1 MFMA]--> t3
//  [FUSED] offset conv (32->1152) computed INSIDE k_deform via f16 MFMA
//  deform_conv(x, upsample2x(offsets), wd) -> out (4,64,128,128)
//
//  Round-14 change: k_conv0_mfma widened to 512 threads (8 waves), the
//  same lever that won -7.3us on conv13 in round 13:
//   - stage 1600 floats: 7 -> 4 iters/thread; A-build: 36 -> 18 cols;
//     MFMA N=64 split over wave-groups (waves 0-3 n={0,1}, 4-7 n={2,3}),
//     acc[4] -> acc[2]; pool epilogue 2 px/thread (float2).
//   - Residency exact: 4 blocks x 8 waves = 32 waves/CU (cap), LDS 124KB.
//   - Dataflow/swizzles/MFMA lane maps unchanged (round-5 proven).
//  k_conv13 (512 thr), k_deform (v5 ledger floor), k_wdt = round-13 locked.

#define HX 130
#define WX 130

typedef short bf16x8 __attribute__((ext_vector_type(8)));
typedef _Float16 f16x8 __attribute__((ext_vector_type(8)));
typedef float f32x4 __attribute__((ext_vector_type(4)));

static __device__ __forceinline__ unsigned short f2bf(float f) {
    unsigned u = __float_as_uint(f);
    unsigned r = u + 0x7fff + ((u >> 16) & 1);   // round-to-nearest-even
    return (unsigned short)(r >> 16);
}

// A-tile address (in shorts): row pitch 320, 16B-block swizzle (k_deform v5)
static __device__ __forceinline__ int aoff320(int row, int col) {
    return row * 320 + ((((col >> 3) ^ (row & 7))) << 3) + (col & 7);
}

// A-tile address (in shorts): row pitch 192 (160-col tiles), 16B-block swizzle
static __device__ __forceinline__ int aoff192(int row, int col) {
    return row * 192 + ((((col >> 3) ^ (row & 7))) << 3) + (col & 7);
}

// A-tile address (in shorts): row pitch 80 (64-col 1x1 tile), same family
static __device__ __forceinline__ int aoff80(int row, int col) {
    return row * 80 + ((((col >> 3) ^ (row & 7))) << 3) + (col & 7);
}

// ---------------- K0: weight prep
//  idx <  36864 : wd -> bf16 wdtb[h(2)][oc(64)][col(288)]  (+16 zero tail)
//  idx <  73728 : w3 -> fp16 w3h[1152][32]
//  idx < 114688 : w0 -> bf16 w0b[cig(4)][oc(64)][160]; col=ci_l*9+kk, pad 0
//  idx < 124928 : w2 -> bf16 w2b[cig(2)][oc(32)][160]; col=ci_l*9+kk, pad 0
//  idx < 126976 : w1 -> bf16 w1b[oc(32)][64] (contiguous copy-convert)
__global__ __launch_bounds__(256) void k_wdt(const float* __restrict__ wd,
                                             const float* __restrict__ w3,
                                             const float* __restrict__ w0,
                                             const float* __restrict__ w2,
                                             const float* __restrict__ w1,
                                             unsigned short* __restrict__ wdtb,
                                             __half* __restrict__ w3h,
                                             unsigned short* __restrict__ w0b,
                                             unsigned short* __restrict__ w2b,
                                             unsigned short* __restrict__ w1b) {
    int idx = blockIdx.x * 256 + threadIdx.x;   // grid 496*256 = 126976
    if (idx < 36864) {
        int o = idx / 576;
        int rem = idx - o * 576;
        int c = rem / 9;
        int kk = rem - c * 9;
        int h = c >> 5;
        int c5 = c & 31;
        int col = (c5 >> 4) * 144 + ((c5 >> 3) & 1) * 72 + (c5 & 7) * 9 + kk;
        wdtb[(size_t)(h * 64 + o) * 288 + col] = f2bf(wd[idx]);
        if (idx < 16) wdtb[36864 + idx] = 0;    // tail pad: guard 0*NaN
    } else if (idx < 73728) {
        int i2 = idx - 36864;
        w3h[i2] = __float2half_rn(w3[i2]);
    } else if (idx < 114688) {
        int i3 = idx - 73728;                   // 0..40959
        int row = i3 / 160;                     // cig*64 + oc
        int col = i3 - row * 160;
        int cig = row >> 6, oc = row & 63;
        unsigned short v = 0;
        if (col < 144) {
            int ci = (col * 57) >> 9;           // /9, valid col<144
            int kk = col - ci * 9;
            v = f2bf(w0[(size_t)(oc * 64 + cig * 16 + ci) * 9 + kk]);
        }
        w0b[i3] = v;
    } else if (idx < 124928) {
        int i4 = idx - 114688;                  // 0..10239
        int row = i4 / 160;                     // cig*32 + oc
        int col = i4 - row * 160;
        int cig = row >> 5, oc = row & 31;
        unsigned short v = 0;
        if (col < 144) {
            int ci = (col * 57) >> 9;
            int kk = col - ci * 9;
            v = f2bf(w2[(size_t)(oc * 32 + cig * 16 + ci) * 9 + kk]);
        }
        w2b[i4] = v;
    } else {
        int i5 = idx - 124928;                  // 0..2047
        w1b[i5] = f2bf(w1[i5]);
    }
}

// ---------------- K1: conv3x3 valid (64->64) via MFMA + bias + maxpool -> p1
// grid 1024 = b(4) * ty(16) * tx(16); block 512 = 8 waves (32 waves/CU).
// Same dataflow as round-5 256-thread version; tid->task maps rescaled.
__global__ __launch_bounds__(512) void k_conv0_mfma(const float* __restrict__ x,
                                                    const unsigned short* __restrict__ w0b,
                                                    const float* __restrict__ b0,
                                                    float* __restrict__ p1) {
    int blk = blockIdx.x;
    int tx = blk & 15;
    int ty = (blk >> 4) & 15;
    int b = blk >> 8;
    int tid = threadIdx.x;
    int w = tid >> 6;             // 0..7
    int lane = tid & 63;
    int lm = lane & 15;
    int lq = lane >> 4;
    int wl = w & 3;               // A row-tile within group
    int ng = w >> 2;              // N half (0/1): n = ng*2 + nn
    int oy0 = ty * 8, ox0 = tx * 8;

    __shared__ __align__(16) unsigned short alds[64 * 192];   // 24576 B
    __shared__ __align__(16) float xlds[1600];                //  6400 B

    f32x4 acc[2];
    #pragma unroll
    for (int n = 0; n < 2; ++n) acc[n] = (f32x4){0.f, 0.f, 0.f, 0.f};

    if (tid < 128) {
        *(bf16x8*)&alds[aoff192(tid >> 1, 144 + (tid & 1) * 8)] =
            (bf16x8){0, 0, 0, 0, 0, 0, 0, 0};
    }

    const float* xb = x + (size_t)(b * 64) * (HX * WX) + oy0 * WX + ox0;
    int apx = tid >> 3;           // 0..63 conv px (py*8+pxx)
    int acq = tid & 7;            // col slice (18 cols each)
    int py = apx >> 3, pxx = apx & 7;

    for (int cig = 0; cig < 4; ++cig) {
        #pragma unroll
        for (int j = 0; j < 4; ++j) {
            int i = tid + j * 512;
            if (i < 1600) {
                int ci = i / 100;
                int rem = i - ci * 100;
                int rr = rem / 10, cc = rem - rr * 10;
                xlds[i] = xb[(size_t)(cig * 16 + ci) * (HX * WX) + rr * WX + cc];
            }
        }
        __syncthreads();
        #pragma unroll
        for (int jj = 0; jj < 18; ++jj) {
            int col = acq * 18 + jj;
            int ci = (col * 57) >> 9;     // /9
            int kk = col - ci * 9;
            int ky = kk / 3, kx = kk - ky * 3;
            alds[aoff192(apx, col)] =
                f2bf(xlds[ci * 100 + (py + ky) * 10 + (pxx + kx)]);
        }
        __syncthreads();
        int arow = wl * 16 + lm;
        const unsigned short* bbase = w0b + (size_t)cig * 64 * 160;
        #pragma unroll
        for (int ks = 0; ks < 5; ++ks) {
            bf16x8 a = *(const bf16x8*)&alds[aoff192(arow, ks * 32 + lq * 8)];
            #pragma unroll
            for (int nn = 0; nn < 2; ++nn) {
                int n = ng * 2 + nn;
                bf16x8 bb = *(const bf16x8*)(bbase + (size_t)(n * 16 + lm) * 160
                                             + ks * 32 + lq * 8);
                acc[nn] = __builtin_amdgcn_mfma_f32_16x16x32_bf16(a, bb, acc[nn], 0, 0, 0);
            }
        }
    }

    __syncthreads();
    float* dlds = (float*)alds;   // 64*65 floats
    #pragma unroll
    for (int nn = 0; nn < 2; ++nn) {
        int oc = (ng * 2 + nn) * 16 + lm;
        #pragma unroll
        for (int r = 0; r < 4; ++r) {
            int px = wl * 16 + lq * 4 + r;
            dlds[oc * 65 + px] = acc[nn][r];
        }
    }
    __syncthreads();
    {
        int oc = tid >> 3;        // 0..63
        int rem = tid & 7;
        int ppy = rem >> 1;       // pooled row
        int pph = rem & 1;        // half (2 pooled px)
        float bo = b0[oc];
        const float* dp = &dlds[oc * 65 + (2 * ppy) * 8 + pph * 4];
        float m0 = fmaxf(fmaxf(dp[0], dp[1]), fmaxf(dp[8], dp[9])) + bo;
        float m1 = fmaxf(fmaxf(dp[2], dp[3]), fmaxf(dp[10], dp[11])) + bo;
        *(float2*)(p1 + (((size_t)b * 64 + oc) * 64 + ty * 4 + ppy) * 64
                   + tx * 4 + pph * 2) = make_float2(m0, m1);
    }
}

// ---------------- K2: FUSED 1x1 (64->32) + 3x3 pad=1 (32->32) -> t3
// grid 256 = b(4) * ty(8) * tx(8); block 512 = 8 waves. (round-13 proven)
__global__ __launch_bounds__(512) void k_conv13(const float* __restrict__ p1,
                                                const unsigned short* __restrict__ w1b,
                                                const float* __restrict__ b1,
                                                const unsigned short* __restrict__ w2b,
                                                const float* __restrict__ b2,
                                                float* __restrict__ t3) {
    int blk = blockIdx.x;
    int tx = blk & 7;
    int ty = (blk >> 3) & 7;
    int b = blk >> 6;
    int tid = threadIdx.x;
    int w = tid >> 6;             // 0..7
    int lane = tid & 63;
    int lm = lane & 15;
    int lq = lane >> 4;
    int oy0 = ty * 8, ox0 = tx * 8;

    __shared__ __align__(16) float t2b[32 * 100];            // 12800 B
    __shared__ __align__(16) unsigned short areg[64 * 192];  // 24576 B (A1/A3/dlds)

    // ---- step 1: stage p1 halo -> A1 bf16 [px100][ci64] (zero-padded)
    const float* pb = p1 + (size_t)(b * 64) * 4096;
    #pragma unroll
    for (int j = 0; j < 13; ++j) {
        int i = tid + j * 512;        // 0..6399
        if (i < 6400) {
            int ci = i / 100;
            int pp = i - ci * 100;
            int rr = pp / 10, cc = pp - rr * 10;
            int gy = oy0 + rr - 1, gx = ox0 + cc - 1;
            bool ok = (gy >= 0) & (gy < 64) & (gx >= 0) & (gx < 64);
            float v = ok ? pb[(size_t)ci * 4096 + gy * 64 + gx] : 0.f;
            areg[aoff80(pp, ci)] = f2bf(v);
        }
    }
    __syncthreads();

    // ---- step 2: 1x1 MFMA. 7 row-tiles over waves 0..6 (wave 7 idle).
    if (w < 7) {
        int rt = w;
        f32x4 a1[2];
        a1[0] = (f32x4){0.f, 0.f, 0.f, 0.f};
        a1[1] = (f32x4){0.f, 0.f, 0.f, 0.f};
        #pragma unroll
        for (int ks = 0; ks < 2; ++ks) {
            bf16x8 a = *(const bf16x8*)&areg[aoff80(rt * 16 + lm, ks * 32 + lq * 8)];
            #pragma unroll
            for (int n = 0; n < 2; ++n) {
                bf16x8 bb = *(const bf16x8*)(w1b + (size_t)(n * 16 + lm) * 64
                                             + ks * 32 + lq * 8);
                a1[n] = __builtin_amdgcn_mfma_f32_16x16x32_bf16(a, bb, a1[n], 0, 0, 0);
            }
        }
        #pragma unroll
        for (int n = 0; n < 2; ++n) {
            int oc = n * 16 + lm;
            float bv = b1[oc];
            #pragma unroll
            for (int r = 0; r < 4; ++r) {
                int px = rt * 16 + lq * 4 + r;
                if (px < 100) t2b[oc * 100 + px] = a1[n][r] + bv;
            }
        }
    }
    __syncthreads();              // t2b complete; A1 dead

    // ---- steps 3/4: conv3 via 2 cig rounds on A3 [64px][144+16pad]
    int apx = tid >> 3, acq = tid & 7;
    int py = apx >> 3, pxx = apx & 7;
    int wl = w & 3;               // A row-tile within group
    int ng = w >> 2;              // N half (0/1)
    f32x4 acc3 = (f32x4){0.f, 0.f, 0.f, 0.f};
    if (tid < 128) {              // zero pad cols 144..159 (after A1 reads done)
        *(bf16x8*)&areg[aoff192(tid >> 1, 144 + (tid & 1) * 8)] =
            (bf16x8){0, 0, 0, 0, 0, 0, 0, 0};
    }
    #pragma unroll 1
    for (int cig = 0; cig < 2; ++cig) {
        __syncthreads();          // pad visible (cig0) / prev MFMA reads done
        #pragma unroll
        for (int jj = 0; jj < 18; ++jj) {
            int col = acq * 18 + jj;
            int ci = (col * 57) >> 9;
            int kk = col - ci * 9;
            int ky = kk / 3, kx = kk - ky * 3;
            areg[aoff192(apx, col)] =
                f2bf(t2b[(cig * 16 + ci) * 100 + (py + ky) * 10 + (pxx + kx)]);
        }
        __syncthreads();
        int arow = wl * 16 + lm;
        const unsigned short* bbase = w2b + (size_t)cig * 32 * 160;
        #pragma unroll
        for (int ks = 0; ks < 5; ++ks) {
            bf16x8 a = *(const bf16x8*)&areg[aoff192(arow, ks * 32 + lq * 8)];
            bf16x8 bb = *(const bf16x8*)(bbase + (size_t)(ng * 16 + lm) * 160
                                         + ks * 32 + lq * 8);
            acc3 = __builtin_amdgcn_mfma_f32_16x16x32_bf16(a, bb, acc3, 0, 0, 0);
        }
    }

    // ---- epilogue: D[64px][32oc] -> LDS -> bias -> t3
    __syncthreads();
    float* dlds = (float*)areg;   // 32*65 floats = 8320 B
    {
        int oc = ng * 16 + lm;
        #pragma unroll
        for (int r = 0; r < 4; ++r) {
            int px = wl * 16 + lq * 4 + r;
            dlds[oc * 65 + px] = acc3[r];
        }
    }
    __syncthreads();
    {
        int oc = tid >> 4;        // 0..31
        int rem = tid & 15;
        int r = rem >> 1;         // out row within region
        int xh = rem & 1;         // half-row (4 px)
        float bo = b2[oc];
        const float* dp = &dlds[oc * 65 + r * 8 + xh * 4];
        float* op = t3 + ((size_t)(b * 32 + oc) * 64 + oy0 + r) * 64 + ox0 + xh * 4;
        *(float4*)(op) = make_float4(dp[0] + bo, dp[1] + bo, dp[2] + bo, dp[3] + bo);
    }
}

// ---------------- K5: deformable conv (v5 body, proven 84us) + XCD swizzle
// grid 1024. Bijective remap: XCD k=blk&7 hosts batch b=k&3 only (L2
// locality heuristic, measured-neutral but free). s_setprio(1) wraps
// phase-2 MFMA. Per sub-phase s: 18 f16-MFMA offset tiles -> soff; 2304
// gather tasks -> bf16 A-tile; per half: 9x4 bf16-MFMA D[64px][64oc].
__global__ __launch_bounds__(256, 3) void k_deform(const float* __restrict__ x,
                                                   const float* __restrict__ t3,
                                                   const __half* __restrict__ w3h,
                                                   const float* __restrict__ b3,
                                                   const unsigned short* __restrict__ wdtb,
                                                   float* __restrict__ out) {
    int blk = blockIdx.x;
    int k8 = blk & 7;             // XCD (dispatch round-robin heuristic)
    int j8 = blk >> 3;            // 0..127
    int b = k8 & 3;               // batch clustered per XCD
    int strip = j8 * 2 + (k8 >> 2);   // 0..255, bijective
    int tid = threadIdx.x;
    int po0 = strip * 16;
    int qy = po0 >> 6;            // strip lies in one quad-row
    int qx0 = po0 & 63;
    int w = tid >> 6;             // wave id
    int lane = tid & 63;
    int lm = lane & 15;
    int lq = lane >> 4;
    int tq = tid & 15;            // pooled-px column this thread serves (fixed)
    int kb = tid >> 4;            // kcol = it*16 + kb

    __shared__ __align__(16) unsigned short alds[64 * 320];   // 40960 B
    __shared__ __align__(16) __half2 soff[2304];              //  9216 B
    __shared__ __align__(16) _Float16 st3t[16 * 40];          //  1280 B

    f32x4 acc[4];
    #pragma unroll
    for (int n = 0; n < 4; ++n) acc[n] = (f32x4){0.f, 0.f, 0.f, 0.f};

    const float* xb = x + (size_t)b * 64 * HX * WX;
    float fybase = (float)(2 * qy);
    float fxbase = (float)(2 * (qx0 + tq));

    // ---- stage t3 tile (32 ci x 16 px) to LDS as fp16, px-major pitch 40
    {
        int px = tid & 15, ci0 = tid >> 4;    // ci0 0..15
        const float* t3p = t3 + (size_t)b * 32 * 4096 + (qy * 64 + qx0 + px);
        st3t[px * 40 + ci0]      = (_Float16)t3p[(size_t)ci0 * 4096];
        st3t[px * 40 + ci0 + 16] = (_Float16)t3p[(size_t)(ci0 + 16) * 4096];
    }
    __syncthreads();
    // B-frag (t3) for the offset MFMA: lane holds t3[px=lm][ci=lq*8+j].
    const f16x8 bfrag = *(const f16x8*)&st3t[lm * 40 + lq * 8];

    for (int h = 0; h < 2; ++h) {
        #pragma unroll 1
        for (int sl = 0; sl < 2; ++sl) {
            int s = h * 2 + sl;           // sup = 16 channels
            __syncthreads();              // alds+soff free (prev phase done)

            // ---- phase 1a: offsets via f16 MFMA. 18 tiles of 16 off-ch.
            #pragma unroll
            for (int rep = 0; rep < 5; ++rep) {
                int t = rep * 4 + w;
                if (rep == 4) { if (w >= 2) break; t = 16 + w; }
                const f16x8 afrag = *(const f16x8*)((const _Float16*)w3h
                        + (size_t)(s * 288 + t * 16 + lm) * 32 + lq * 8);
                f32x4 d = __builtin_amdgcn_mfma_f32_16x16x32_f16(
                        afrag, bfrag, (f32x4){0.f, 0.f, 0.f, 0.f}, 0, 0, 0);
                float4 bq = *(const float4*)(b3 + s * 288 + t * 16 + lq * 4);
                int p0 = (t * 8 + lq * 2) * 16 + lm;   // pair-slot kcol*16+px
                soff[p0]      = __floats2half2_rn(d[0] + bq.x, d[1] + bq.y);
                soff[p0 + 16] = __floats2half2_rn(d[2] + bq.z, d[3] + bq.w);
            }
            __syncthreads();              // soff visible

            // ---- phase 1b: prefetch 9 offset pairs (word = it*256 + tid)
            __half2 o2h[9];
            #pragma unroll
            for (int it = 0; it < 9; ++it)
                o2h[it] = soff[it * 256 + tid];
            // bilinear gather -> 4 bf16 A-tile rows per task
            #pragma unroll
            for (int it = 0; it < 9; ++it) {
                int kcol = it * 16 + kb;      // 0..143
                int lc = kcol >= 72;
                int ckk = kcol - 72 * lc;     // 0..71
                int ch = (ckk * 57) >> 9;     // /9
                int kk = ckk - ch * 9;
                int c = s * 16 + lc * 8 + ch;
                int clocal = sl * 144 + kcol; // A column 0..287
                float2 off = __half22float2(o2h[it]);
                float py = off.x + fybase + (float)(kk / 3);
                float px = off.y + fxbase + (float)(kk % 3);
                float y0f = floorf(py), x0f = floorf(px);
                float fy = py - y0f, fx = px - x0f;
                int y0 = (int)y0f, x0 = (int)x0f;
                const float* xp = xb + (size_t)c * (HX * WX);
                float tv[3][3];
                bool fastok = (y0 >= 0) & (y0 <= HX - 3) & (x0 >= 0) & (x0 <= WX - 3);
                if (__all(fastok)) {
                    // whole wave in-bounds: even-aligned float2 pair per row
                    int xe = x0 & ~1;         // even -> 8B-aligned (WX even)
                    int odd = x0 & 1;
                    const float* rp = xp + y0 * WX + xe;
                    #pragma unroll
                    for (int r = 0; r < 3; ++r) {
                        float2 A = *(const float2*)(rp);
                        float2 B = *(const float2*)(rp + 2);
                        tv[r][0] = odd ? A.y : A.x;
                        tv[r][1] = odd ? B.x : A.y;
                        tv[r][2] = odd ? B.y : B.x;
                        rp += WX;
                    }
                } else {
                    #pragma unroll
                    for (int r = 0; r < 3; ++r) {
                        int yy = y0 + r;
                        bool vy = (yy >= 0) & (yy < HX);
                        int yc = min(max(yy, 0), HX - 1);
                        #pragma unroll
                        for (int sx = 0; sx < 3; ++sx) {
                            int xx = x0 + sx;
                            bool vx = (xx >= 0) & (xx < WX);
                            int xc = min(max(xx, 0), WX - 1);
                            float val = xp[yc * WX + xc];
                            tv[r][sx] = (vy & vx) ? val : 0.f;
                        }
                    }
                }
                float h0[3], h1[3];
                #pragma unroll
                for (int r = 0; r < 3; ++r) {
                    h0[r] = tv[r][0] + fx * (tv[r][1] - tv[r][0]);
                    h1[r] = tv[r][1] + fx * (tv[r][2] - tv[r][1]);
                }
                alds[aoff320(0 * 16 + tq, clocal)] = f2bf(h0[0] + fy * (h0[1] - h0[0]));
                alds[aoff320(1 * 16 + tq, clocal)] = f2bf(h1[0] + fy * (h1[1] - h1[0]));
                alds[aoff320(2 * 16 + tq, clocal)] = f2bf(h0[1] + fy * (h0[2] - h0[1]));
                alds[aoff320(3 * 16 + tq, clocal)] = f2bf(h1[1] + fy * (h1[2] - h1[1]));
            }
        }
        __syncthreads();          // A-tile (288 cols) visible

        // ---- phase 2: D[64px][64oc] += V[64][288] . W^T  (MFMA bf16)
        int arow = w * 16 + lm;
        const unsigned short* bbase = wdtb + (size_t)(h * 64) * 288;
        __builtin_amdgcn_s_setprio(1);
        #pragma unroll
        for (int ks = 0; ks < 9; ++ks) {
            bf16x8 a = *(const bf16x8*)&alds[aoff320(arow, ks * 32 + lq * 8)];
            #pragma unroll
            for (int n = 0; n < 4; ++n) {
                bf16x8 bb = *(const bf16x8*)(bbase + (size_t)(n * 16 + lm) * 288
                                             + ks * 32 + lq * 8);
                acc[n] = __builtin_amdgcn_mfma_f32_16x16x32_bf16(a, bb, acc[n], 0, 0, 0);
            }
        }
        __builtin_amdgcn_s_setprio(0);
    }

    // ---- epilogue via LDS: D lane layout -> [oc][px] -> coalesced stores
    __syncthreads();              // all phase-2 reads of alds complete
    float* dlds = (float*)alds;   // 64*65 = 4160 floats
    #pragma unroll
    for (int n = 0; n < 4; ++n) {
        int oc = n * 16 + lm;
        #pragma unroll
        for (int r = 0; r < 4; ++r) {
            int px = w * 16 + lq * 4 + r;     // = sub*16 + q
            dlds[oc * 65 + px] = acc[n][r];
        }
    }
    __syncthreads();
    {
        int oc = tid >> 2;
        int sy = (tid >> 1) & 1;
        int qh = (tid & 1) * 8;
        float* orow = out + (((size_t)b * 64 + oc) * 128 + 2 * qy + sy) * 128 + 2 * qx0;
        const float* d0 = &dlds[oc * 65 + (sy * 2 + 0) * 16];
        const float* d1 = &dlds[oc * 65 + (sy * 2 + 1) * 16];
        #pragma unroll
        for (int i = 0; i < 8; ++i) {
            int q = qh + i;
            *(float2*)(orow + 2 * q) = make_float2(d0[q], d1[q]);
        }
    }
}

extern "C" void kernel_launch(void* const* d_in, const int* in_sizes, int n_in,
                              void* d_out, int out_size, void* d_ws, size_t ws_size,
                              hipStream_t stream) {
    const float* x  = (const float*)d_in[0];
    const float* w0 = (const float*)d_in[1];
    const float* b0 = (const float*)d_in[2];
    const float* w1 = (const float*)d_in[3];
    const float* b1 = (const float*)d_in[4];
    const float* w2 = (const float*)d_in[5];
    const float* b2 = (const float*)d_in[6];
    const float* w3 = (const float*)d_in[7];
    const float* b3 = (const float*)d_in[8];
    const float* wd = (const float*)d_in[9];
    float* out = (float*)d_out;

    float* ws = (float*)d_ws;
    float* p1    = ws;                       // 1,048,576 floats
    float* t3    = p1 + 1048576;             //   524,288
    unsigned short* wdtb = (unsigned short*)(t3 + 524288);  // 36,864 + 16 pad
    __half* w3h = (__half*)(wdtb + 36880);   // 36,864 fp16 (16B-aligned)
    unsigned short* w0b = (unsigned short*)(w3h + 36864);   // 40,960 bf16
    unsigned short* w2b = w0b + 40960;                      // 10,240 bf16
    unsigned short* w1b = w2b + 10240;                      //  2,048 bf16

    k_wdt<<<496, 256, 0, stream>>>(wd, w3, w0, w2, w1, wdtb, w3h, w0b, w2b, w1b);
    k_conv0_mfma<<<1024, 512, 0, stream>>>(x, w0b, b0, p1);
    k_conv13<<<256, 512, 0, stream>>>(p1, w1b, b1, w2b, b2, t3);
    k_deform<<<1024, 256, 0, stream>>>(x, t3, w3h, b3, wdtb, out);
}